// Round 4
// baseline (1252.962 us; speedup 1.0000x reference)
//
#include <hip/hip_runtime.h>
#include <math.h>

#define N_BASIS 16
#define HIDDEN 64
#define OUT_DIM 128
#define NN 100000
#define NE 1600000
#define NPB 16
#define NTILES (NN/NPB)      // 6250
#define SCAN_NB 391          // ceil(NN/256)
#define GATHER_BLOCKS 2048

typedef __bf16 bfrag __attribute__((ext_vector_type(8)));
typedef float  ffrag __attribute__((ext_vector_type(4)));

union BF8 { bfrag v; uint4 u4; uint2 u2[2]; };

__device__ __forceinline__ unsigned pack_bf2(float lo, float hi) {
    union { float f; unsigned u; } a, b;
    a.f = lo; b.f = hi;
    unsigned ra = a.u + 0x7FFFu + ((a.u >> 16) & 1u);
    unsigned rb = b.u + 0x7FFFu + ((b.u >> 16) & 1u);
    return (ra >> 16) | (rb & 0xFFFF0000u);
}

__device__ __forceinline__ float silu_f(float x) {          // fast: exp + rcp
    return x * __builtin_amdgcn_rcpf(1.0f + __expf(-x));
}

// Old-style feat (fallback path only)
__device__ __forceinline__ void compute_feat(
    float rx, float ry, float rz,
    const float* __restrict__ sC, const float* __restrict__ sWd,
    const float* __restrict__ sShW, const float* __restrict__ sShB,
    float* feat)
{
    float d2 = rx*rx + ry*ry + rz*rz;
    float d = fmaxf(sqrtf(d2), 1e-6f);
    float inv = 1.0f / d;
    float ux = rx*inv, uy = ry*inv, uz = rz*inv;
    #pragma unroll
    for (int m = 0; m < 16; ++m) {
        float t = d - sC[m];
        feat[m] = __expf(-fabsf(sWd[m]) * t * t);
    }
    const float c0 = 0.28209479177387814f;
    const float c1 = 0.4886025119029199f;
    const float c2 = 1.0925484305920792f;
    const float c3 = 0.31539156525252005f;
    const float c4 = 0.5462742152960396f;
    float sh0 = c0;
    float sh1 = c1*uy, sh2 = c1*uz, sh3 = c1*ux;
    float sh4 = c2*ux*uy, sh5 = c2*uy*uz;
    float sh6 = c3*(2.0f*uz*uz - ux*ux - uy*uy);
    float sh7 = c2*ux*uz, sh8 = c4*(ux*ux - uy*uy);
    #pragma unroll
    for (int m = 0; m < 16; ++m) {
        float a = sShB[m];
        a += sh0*sShW[0*16+m]; a += sh1*sShW[1*16+m]; a += sh2*sShW[2*16+m];
        a += sh3*sShW[3*16+m]; a += sh4*sShW[4*16+m]; a += sh5*sShW[5*16+m];
        a += sh6*sShW[6*16+m]; a += sh7*sShW[7*16+m]; a += sh8*sShW[8*16+m];
        feat[16+m] = a;
    }
}

// Fold sh_w/sh_b into both MLPs' first layers: w1e/b1e (edge) + zwe/zbe (zinc)
__global__ __launch_bounds__(64) void prep_kernel(
    const float* __restrict__ sh_w, const float* __restrict__ sh_b,
    const float* __restrict__ w1, const float* __restrict__ b1,
    const float* __restrict__ znw, const float* __restrict__ znb,
    float* __restrict__ w1e, float* __restrict__ b1e,
    float* __restrict__ zwe, float* __restrict__ zbe)
{
    int j = threadIdx.x;
    #pragma unroll
    for (int k = 0; k < 16; ++k) {
        w1e[k*64 + j] = w1[k*64 + j];
        zwe[k*64 + j] = znw[k*64 + j];
    }
    for (int s = 0; s < 9; ++s) {
        float a = 0.0f, z = 0.0f;
        for (int m = 0; m < 16; ++m) {
            a += sh_w[s*16 + m] * w1[(16+m)*64 + j];
            z += sh_w[s*16 + m] * znw[(16+m)*64 + j];
        }
        w1e[(16+s)*64 + j] = a;
        zwe[(16+s)*64 + j] = z;
    }
    #pragma unroll
    for (int s = 25; s < 32; ++s) { w1e[s*64 + j] = 0.0f; zwe[s*64 + j] = 0.0f; }
    float bb = b1[j], zb = znb[j];
    for (int m = 0; m < 16; ++m) {
        bb += sh_b[m] * w1[(16+m)*64 + j];
        zb += sh_b[m] * znw[(16+m)*64 + j];
    }
    b1e[j] = bb;
    zbe[j] = zb;
}

// ---------------- counting-sort pipeline ----------------

__global__ __launch_bounds__(256) void hist_kernel(
    const int* __restrict__ ei, int* __restrict__ count)
{
    int e = blockIdx.x * 256 + threadIdx.x;
    atomicAdd(&count[ei[e]], 1);
}

__global__ __launch_bounds__(256) void scan1_kernel(
    int* __restrict__ count, int* __restrict__ bsum)
{
    __shared__ int s[256];
    int t = threadIdx.x;
    int i = blockIdx.x * 256 + t;
    int v = (i < NN) ? count[i] : 0;
    s[t] = v;
    __syncthreads();
    #pragma unroll
    for (int off = 1; off < 256; off <<= 1) {
        int add = (t >= off) ? s[t - off] : 0;
        __syncthreads();
        s[t] += add;
        __syncthreads();
    }
    if (i < NN) count[i] = s[t] - v;
    if (t == 255) bsum[blockIdx.x] = s[255];
}

__global__ __launch_bounds__(512) void scan2_kernel(
    const int* __restrict__ bsum, int* __restrict__ bsumoff)
{
    __shared__ int s[512];
    int t = threadIdx.x;
    int v = (t < SCAN_NB) ? bsum[t] : 0;
    s[t] = v;
    __syncthreads();
    #pragma unroll
    for (int off = 1; off < 512; off <<= 1) {
        int add = (t >= off) ? s[t - off] : 0;
        __syncthreads();
        s[t] += add;
        __syncthreads();
    }
    if (t < SCAN_NB) bsumoff[t] = s[t] - v;
}

__global__ __launch_bounds__(256) void scan3_kernel(
    const int* __restrict__ count, const int* __restrict__ bsumoff,
    int* __restrict__ start, int* __restrict__ cursor)
{
    int i = blockIdx.x * 256 + threadIdx.x;
    if (i < NN) {
        int v = count[i] + bsumoff[blockIdx.x];
        start[i] = v;
        cursor[i] = v;
    }
    if (i == 0) start[NN] = NE;
}

__global__ __launch_bounds__(256) void scatter_kernel(
    const int* __restrict__ ei, int* __restrict__ cursor,
    int* __restrict__ sdj)
{
    int e = blockIdx.x * 256 + threadIdx.x;
    int s = ei[e], d = ei[NE + e];
    int p = atomicAdd(&cursor[s], 1);
    sdj[p] = (d << 4) | (s & 15);
}

// ---------------- persistent MFMA gather ----------------
// Per wave, 64 sorted edges/batch. B-frags built directly in registers
// (lane (lm,q) computes feat[q*8..q*8+7] of edge nt*16+lm).
__global__ __launch_bounds__(256, 2) void gather_mfma2_kernel(
    const float* __restrict__ pos,
    const int* __restrict__ sdj, const int* __restrict__ start,
    const float* __restrict__ rbf_c, const float* __restrict__ rbf_w,
    const float* __restrict__ w1e, const float* __restrict__ b1e,
    const float* __restrict__ w2, const float* __restrict__ b2,
    float* __restrict__ agg)
{
    __shared__ unsigned h1t[4 * 16 * 34];   // [wave][16 e][34 uints] stride 136B
    __shared__ float tile[NPB * 68];        // stride 68: banks (je*4+col)%32 spread
    __shared__ float sPosL[NPB * 3];
    __shared__ int sStart[NPB + 1];

    int tid = threadIdx.x;
    int wave = tid >> 6, lane = tid & 63;
    int lm = lane & 15, q = lane >> 4;

    // persistent register state (loaded once per block)
    bfrag w1f[4];
    #pragma unroll
    for (int mt = 0; mt < 4; ++mt)
        #pragma unroll
        for (int kk = 0; kk < 8; ++kk)
            w1f[mt][kk] = (__bf16)w1e[(q*8 + kk)*64 + mt*16 + lm];
    bfrag w2f[2][4];
    #pragma unroll
    for (int kb = 0; kb < 2; ++kb)
        #pragma unroll
        for (int mt = 0; mt < 4; ++mt)
            #pragma unroll
            for (int kk = 0; kk < 8; ++kk)
                w2f[kb][mt][kk] = (__bf16)w2[(kb*32 + q*8 + kk)*64 + mt*16 + lm];
    ffrag b1v[4], b2v[4];
    #pragma unroll
    for (int mt = 0; mt < 4; ++mt)
        #pragma unroll
        for (int r = 0; r < 4; ++r) {
            b1v[mt][r] = b1e[mt*16 + q*4 + r];
            b2v[mt][r] = b2[mt*16 + q*4 + r];
        }
    float rc[8], rw[8];
    #pragma unroll
    for (int kk = 0; kk < 8; ++kk) {
        rc[kk] = rbf_c[(q & 1)*8 + kk];
        rw[kk] = fabsf(rbf_w[(q & 1)*8 + kk]);
    }
    unsigned* hW = &h1t[wave * 16 * 34];

    const float c0 = 0.28209479177387814f;
    const float c1 = 0.4886025119029199f;
    const float c2 = 1.0925484305920792f;
    const float c3 = 0.31539156525252005f;
    const float c4 = 0.5462742152960396f;

    for (int t = blockIdx.x; t < NTILES; t += gridDim.x) {
        int nlo = t * NPB;
        if (tid < NPB + 1) sStart[tid] = start[nlo + tid];
        if (tid >= 64 && tid < 64 + NPB*3) sPosL[tid - 64] = pos[(size_t)nlo*3 + tid - 64];
        for (int i = tid; i < NPB * 68; i += 256) tile[i] = 0.0f;
        __syncthreads();

        int pbeg = sStart[0], pend = sStart[NPB];
        for (int pb = pbeg + wave * 64; pb < pend; pb += 256) {
            #pragma unroll
            for (int nt = 0; nt < 4; ++nt) {
                int pe = pb + nt*16 + lm;
                int pc = pe < pend ? pe : (pend - 1);
                int v = sdj[pc];
                int d = v >> 4, jn = v & 15;
                float rx = pos[(size_t)d*3+0] - sPosL[jn*3+0];
                float ry = pos[(size_t)d*3+1] - sPosL[jn*3+1];
                float rz = pos[(size_t)d*3+2] - sPosL[jn*3+2];
                float d2 = rx*rx + ry*ry + rz*rz;
                float dd = fmaxf(sqrtf(d2), 1e-6f);
                float inv = __builtin_amdgcn_rcpf(dd);
                float ux = rx*inv, uy = ry*inv, uz = rz*inv;
                float f0,f1,f2,f3,f4,f5,f6,f7;
                if (q < 2) {
                    float t0 = dd - rc[0]; f0 = __expf(-rw[0]*t0*t0);
                    float t1 = dd - rc[1]; f1 = __expf(-rw[1]*t1*t1);
                    float t2 = dd - rc[2]; f2 = __expf(-rw[2]*t2*t2);
                    float t3 = dd - rc[3]; f3 = __expf(-rw[3]*t3*t3);
                    float t4 = dd - rc[4]; f4 = __expf(-rw[4]*t4*t4);
                    float t5 = dd - rc[5]; f5 = __expf(-rw[5]*t5*t5);
                    float t6 = dd - rc[6]; f6 = __expf(-rw[6]*t6*t6);
                    float t7 = dd - rc[7]; f7 = __expf(-rw[7]*t7*t7);
                } else if (q == 2) {
                    f0 = c0;
                    f1 = c1*uy; f2 = c1*uz; f3 = c1*ux;
                    f4 = c2*ux*uy; f5 = c2*uy*uz;
                    f6 = c3*(2.0f*uz*uz - ux*ux - uy*uy);
                    f7 = c2*ux*uz;
                } else {
                    f0 = c4*(ux*ux - uy*uy);
                    f1 = f2 = f3 = f4 = f5 = f6 = f7 = 0.0f;
                }
                BF8 bf;
                bf.u4.x = pack_bf2(f0, f1);
                bf.u4.y = pack_bf2(f2, f3);
                bf.u4.z = pack_bf2(f4, f5);
                bf.u4.w = pack_bf2(f6, f7);

                ffrag a1[4];
                #pragma unroll
                for (int mt = 0; mt < 4; ++mt) a1[mt] = b1v[mt];
                #pragma unroll
                for (int mt = 0; mt < 4; ++mt)
                    a1[mt] = __builtin_amdgcn_mfma_f32_16x16x32_bf16(w1f[mt], bf.v, a1[mt], 0, 0, 0);
                #pragma unroll
                for (int mt = 0; mt < 4; ++mt) {
                    float s0 = silu_f(a1[mt][0]);
                    float s1 = silu_f(a1[mt][1]);
                    float s2 = silu_f(a1[mt][2]);
                    float s3 = silu_f(a1[mt][3]);
                    uint2 w;
                    w.x = pack_bf2(s0, s1);
                    w.y = pack_bf2(s2, s3);
                    *(uint2*)&hW[lm*34 + mt*8 + q*2] = w;
                }
                ffrag a2[4];
                #pragma unroll
                for (int mt = 0; mt < 4; ++mt) a2[mt] = b2v[mt];
                #pragma unroll
                for (int kb = 0; kb < 2; ++kb) {
                    BF8 pf;
                    pf.u2[0] = *(const uint2*)&hW[lm*34 + kb*16 + q*4];
                    pf.u2[1] = *(const uint2*)&hW[lm*34 + kb*16 + q*4 + 2];
                    #pragma unroll
                    for (int mt = 0; mt < 4; ++mt)
                        a2[mt] = __builtin_amdgcn_mfma_f32_16x16x32_bf16(w2f[kb][mt], pf.v, a2[mt], 0, 0, 0);
                }
                if (pe < pend) {
                    float* trow = &tile[jn * 68];
                    #pragma unroll
                    for (int mt = 0; mt < 4; ++mt)
                        #pragma unroll
                        for (int r = 0; r < 4; ++r)
                            atomicAdd(&trow[mt*16 + q*4 + r], a2[mt][r]);
                }
            }
        }
        __syncthreads();
        for (int i = tid; i < NPB * 64; i += 256)
            agg[(size_t)nlo * 64 + i] = tile[(i >> 6) * 68 + (i & 63)];
        __syncthreads();
    }
}

// ---------------- MFMA zinc branch (no LDS) ----------------
__global__ __launch_bounds__(256) void zn_mfma_kernel(
    const float* __restrict__ pos, const float* __restrict__ zinc,
    const float* __restrict__ rbf_c, const float* __restrict__ rbf_w,
    const float* __restrict__ zwe, const float* __restrict__ zbe,
    float* __restrict__ zn_f)
{
    int tid = threadIdx.x;
    int wave = tid >> 6, lane = tid & 63;
    int lm = lane & 15, q = lane >> 4;

    bfrag wf[4];
    #pragma unroll
    for (int mt = 0; mt < 4; ++mt)
        #pragma unroll
        for (int kk = 0; kk < 8; ++kk)
            wf[mt][kk] = (__bf16)zwe[(q*8 + kk)*64 + mt*16 + lm];
    ffrag bz[4];
    #pragma unroll
    for (int mt = 0; mt < 4; ++mt)
        #pragma unroll
        for (int r = 0; r < 4; ++r)
            bz[mt][r] = zbe[mt*16 + q*4 + r];
    float rc[8], rw[8];
    #pragma unroll
    for (int kk = 0; kk < 8; ++kk) {
        rc[kk] = rbf_c[(q & 1)*8 + kk];
        rw[kk] = fabsf(rbf_w[(q & 1)*8 + kk]);
    }
    float zx = zinc[0], zy = zinc[1], zz = zinc[2];

    const float c0 = 0.28209479177387814f;
    const float c1 = 0.4886025119029199f;
    const float c2 = 1.0925484305920792f;
    const float c3 = 0.31539156525252005f;
    const float c4 = 0.5462742152960396f;

    int n0 = (blockIdx.x * 4 + wave) * 64;
    #pragma unroll
    for (int nt = 0; nt < 4; ++nt) {
        int n = n0 + nt*16 + lm;
        int nc = n < NN ? n : NN - 1;
        float rx = pos[(size_t)nc*3+0] - zx;
        float ry = pos[(size_t)nc*3+1] - zy;
        float rz = pos[(size_t)nc*3+2] - zz;
        float d2 = rx*rx + ry*ry + rz*rz;
        float dd = fmaxf(sqrtf(d2), 1e-6f);
        float inv = __builtin_amdgcn_rcpf(dd);
        float ux = rx*inv, uy = ry*inv, uz = rz*inv;
        float f0,f1,f2,f3,f4,f5,f6,f7;
        if (q < 2) {
            float t0 = dd - rc[0]; f0 = __expf(-rw[0]*t0*t0);
            float t1 = dd - rc[1]; f1 = __expf(-rw[1]*t1*t1);
            float t2 = dd - rc[2]; f2 = __expf(-rw[2]*t2*t2);
            float t3 = dd - rc[3]; f3 = __expf(-rw[3]*t3*t3);
            float t4 = dd - rc[4]; f4 = __expf(-rw[4]*t4*t4);
            float t5 = dd - rc[5]; f5 = __expf(-rw[5]*t5*t5);
            float t6 = dd - rc[6]; f6 = __expf(-rw[6]*t6*t6);
            float t7 = dd - rc[7]; f7 = __expf(-rw[7]*t7*t7);
        } else if (q == 2) {
            f0 = c0;
            f1 = c1*uy; f2 = c1*uz; f3 = c1*ux;
            f4 = c2*ux*uy; f5 = c2*uy*uz;
            f6 = c3*(2.0f*uz*uz - ux*ux - uy*uy);
            f7 = c2*ux*uz;
        } else {
            f0 = c4*(ux*ux - uy*uy);
            f1 = f2 = f3 = f4 = f5 = f6 = f7 = 0.0f;
        }
        BF8 bf;
        bf.u4.x = pack_bf2(f0, f1);
        bf.u4.y = pack_bf2(f2, f3);
        bf.u4.z = pack_bf2(f4, f5);
        bf.u4.w = pack_bf2(f6, f7);

        ffrag a[4];
        #pragma unroll
        for (int mt = 0; mt < 4; ++mt) a[mt] = bz[mt];
        #pragma unroll
        for (int mt = 0; mt < 4; ++mt)
            a[mt] = __builtin_amdgcn_mfma_f32_16x16x32_bf16(wf[mt], bf.v, a[mt], 0, 0, 0);
        if (n < NN) {
            #pragma unroll
            for (int mt = 0; mt < 4; ++mt) {
                float4 vv;
                vv.x = silu_f(a[mt][0]);
                vv.y = silu_f(a[mt][1]);
                vv.z = silu_f(a[mt][2]);
                vv.w = silu_f(a[mt][3]);
                *(float4*)&zn_f[(size_t)n*64 + mt*16 + q*4] = vv;
            }
        }
    }
}

// ---------------- fallback kernels (round-1 path) ----------------

__global__ __launch_bounds__(256) void edge_kernel(
    const float* __restrict__ pos, const int* __restrict__ edge_index,
    const float* __restrict__ rbf_c, const float* __restrict__ rbf_w,
    const float* __restrict__ sh_w, const float* __restrict__ sh_b,
    const float* __restrict__ w1, const float* __restrict__ b1,
    const float* __restrict__ w2, const float* __restrict__ b2,
    float* __restrict__ agg)
{
    __shared__ float sW1[2048];
    __shared__ float sW2[4096];
    __shared__ float sShW[144], sShB[16], sC[16], sWd[16], sB1[64], sB2[64];
    int tid = threadIdx.x;
    for (int i = tid; i < 2048; i += 256) sW1[i] = w1[i];
    for (int i = tid; i < 4096; i += 256) sW2[i] = w2[i];
    if (tid < 144) sShW[tid] = sh_w[tid];
    if (tid < 16) { sShB[tid] = sh_b[tid]; sC[tid] = rbf_c[tid]; sWd[tid] = rbf_w[tid]; }
    if (tid < 64) sB1[tid] = b1[tid];
    if (tid >= 64 && tid < 128) sB2[tid-64] = b2[tid-64];
    __syncthreads();

    int e = blockIdx.x * 256 + tid;
    int s   = edge_index[e];
    int dst = edge_index[NE + e];
    const float* ps = pos + 3*(size_t)s;
    const float* pd = pos + 3*(size_t)dst;
    float rx = pd[0]-ps[0], ry = pd[1]-ps[1], rz = pd[2]-ps[2];
    float feat[32];
    compute_feat(rx, ry, rz, sC, sWd, sShW, sShB, feat);

    float h2[64];
    #pragma unroll
    for (int o = 0; o < 64; ++o) h2[o] = sB2[o];

    #pragma unroll 1
    for (int jc = 0; jc < 8; ++jc) {
        float h1c[8];
        #pragma unroll
        for (int jj = 0; jj < 8; ++jj) h1c[jj] = sB1[jc*8+jj];
        #pragma unroll
        for (int k = 0; k < 32; ++k) {
            float f = feat[k];
            #pragma unroll
            for (int jj = 0; jj < 8; ++jj) h1c[jj] += f * sW1[k*64 + jc*8 + jj];
        }
        #pragma unroll
        for (int jj = 0; jj < 8; ++jj) h1c[jj] = silu_f(h1c[jj]);
        #pragma unroll
        for (int jj = 0; jj < 8; ++jj) {
            float v = h1c[jj];
            #pragma unroll
            for (int o = 0; o < 64; ++o) h2[o] += v * sW2[(jc*8+jj)*64 + o];
        }
    }
    size_t base = (size_t)s * 64;
    #pragma unroll
    for (int o = 0; o < 64; ++o)
        unsafeAtomicAdd(&agg[base + o], h2[o]);
}

__global__ __launch_bounds__(256) void zn_kernel(
    const float* __restrict__ pos, const float* __restrict__ zinc_pos,
    const float* __restrict__ rbf_c, const float* __restrict__ rbf_w,
    const float* __restrict__ sh_w, const float* __restrict__ sh_b,
    const float* __restrict__ zn_w, const float* __restrict__ zn_b,
    float* __restrict__ zn_f)
{
    __shared__ float sW[2048];
    __shared__ float sShW[144], sShB[16], sC[16], sWd[16], sB[64];
    int tid = threadIdx.x;
    for (int i = tid; i < 2048; i += 256) sW[i] = zn_w[i];
    if (tid < 144) sShW[tid] = sh_w[tid];
    if (tid < 16) { sShB[tid] = sh_b[tid]; sC[tid] = rbf_c[tid]; sWd[tid] = rbf_w[tid]; }
    if (tid < 64) sB[tid] = zn_b[tid];
    __syncthreads();
    int n = blockIdx.x * 256 + tid;
    if (n >= NN) return;
    float rx = pos[n*3+0] - zinc_pos[0];
    float ry = pos[n*3+1] - zinc_pos[1];
    float rz = pos[n*3+2] - zinc_pos[2];
    float feat[32];
    compute_feat(rx, ry, rz, sC, sWd, sShW, sShB, feat);
    #pragma unroll 1
    for (int jc = 0; jc < 8; ++jc) {
        float h[8];
        #pragma unroll
        for (int jj = 0; jj < 8; ++jj) h[jj] = sB[jc*8+jj];
        #pragma unroll
        for (int k = 0; k < 32; ++k) {
            float f = feat[k];
            #pragma unroll
            for (int jj = 0; jj < 8; ++jj) h[jj] += f * sW[k*64 + jc*8 + jj];
        }
        #pragma unroll
        for (int jj = 0; jj < 8; ++jj)
            zn_f[(size_t)n*64 + jc*8 + jj] = silu_f(h[jj]);
    }
}

// ---------------- output projection + LN + SiLU ----------------

__global__ __launch_bounds__(256) void out_kernel(
    const float* __restrict__ agg, const float* __restrict__ zn_f,
    const float* __restrict__ np_w, const float* __restrict__ np_b,
    const float* __restrict__ ln_g, const float* __restrict__ ln_b,
    float* __restrict__ out)
{
    __shared__ float sX[128*36];
    __shared__ float sH[32*130];
    __shared__ float sMu[32], sVar[32];
    int tid = threadIdx.x;
    int o = tid & 127;
    int nb = (tid >> 7) * 16;
    float bias = np_b[o];
    float g = ln_g[o], bta = ln_b[o];

    for (int n0 = blockIdx.x * 32; n0 < NN; n0 += gridDim.x * 32) {
        for (int i = tid; i < 4096; i += 256) {
            int n = i >> 7, k = i & 127;
            float v = (k < 64) ? agg[(size_t)(n0+n)*64 + k]
                               : zn_f[(size_t)(n0+n)*64 + (k-64)];
            sX[k*36 + n] = v;
        }
        __syncthreads();
        float acc[16];
        #pragma unroll
        for (int i = 0; i < 16; ++i) acc[i] = bias;
        #pragma unroll 4
        for (int k = 0; k < 128; ++k) {
            float w = np_w[k*128 + o];
            const float* xr = &sX[k*36 + nb];
            #pragma unroll
            for (int i = 0; i < 16; ++i) acc[i] += w * xr[i];
        }
        #pragma unroll
        for (int i = 0; i < 16; ++i) sH[(nb+i)*130 + o] = acc[i];
        __syncthreads();
        if (tid < 32) {
            float s = 0.0f, sq = 0.0f;
            for (int oo = 0; oo < 128; ++oo) {
                float v = sH[tid*130 + oo];
                s += v; sq += v*v;
            }
            float mu = s * (1.0f/128.0f);
            sMu[tid] = mu;
            sVar[tid] = sq * (1.0f/128.0f) - mu*mu;
        }
        __syncthreads();
        #pragma unroll
        for (int i = 0; i < 16; ++i) {
            int n = nb + i;
            float y = (acc[i] - sMu[n]) * rsqrtf(sVar[n] + 1e-5f) * g + bta;
            out[(size_t)(n0+n)*128 + o] = silu_f(y);
        }
        __syncthreads();
    }
}

extern "C" void kernel_launch(void* const* d_in, const int* in_sizes, int n_in,
                              void* d_out, int out_size, void* d_ws, size_t ws_size,
                              hipStream_t stream) {
    const float* pos   = (const float*)d_in[0];
    const float* zinc  = (const float*)d_in[1];
    const int*   ei    = (const int*)  d_in[2];
    const float* rbf_c = (const float*)d_in[3];
    const float* rbf_w = (const float*)d_in[4];
    const float* sh_w  = (const float*)d_in[5];
    const float* sh_b  = (const float*)d_in[6];
    const float* pm_w1 = (const float*)d_in[7];
    const float* pm_b1 = (const float*)d_in[8];
    const float* pm_w2 = (const float*)d_in[9];
    const float* pm_b2 = (const float*)d_in[10];
    const float* zn_w  = (const float*)d_in[11];
    const float* zn_b  = (const float*)d_in[12];
    const float* np_w  = (const float*)d_in[13];
    const float* np_b  = (const float*)d_in[14];
    const float* ln_g  = (const float*)d_in[15];
    const float* ln_b  = (const float*)d_in[16];
    float* out  = (float*)d_out;

    float* agg  = (float*)d_ws;                        // NN*64 f
    float* zn_f = agg + (size_t)NN * 64;               // NN*64 f
    int* count   = (int*)(zn_f + (size_t)NN * 64);     // NN
    int* start   = count + NN;                         // NN+1
    int* cursor  = start + NN + 1;                     // NN
    int* bsum    = cursor + NN;                        // 512
    int* bsumoff = bsum + 512;                         // 512
    int* sdj     = bsumoff + 512;                      // NE
    float* w1e   = (float*)(sdj + NE);                 // 2048
    float* b1e   = w1e + 2048;                         // 64
    float* zwe   = b1e + 64;                           // 2048
    float* zbe   = zwe + 2048;                         // 64
    size_t needed = (size_t)((char*)(zbe + 64) - (char*)d_ws);

    if (ws_size >= needed) {
        prep_kernel<<<1, 64, 0, stream>>>(sh_w, sh_b, pm_w1, pm_b1, zn_w, zn_b,
                                          w1e, b1e, zwe, zbe);
        hipMemsetAsync(count, 0, NN * sizeof(int), stream);
        hist_kernel<<<NE/256, 256, 0, stream>>>(ei, count);
        scan1_kernel<<<SCAN_NB, 256, 0, stream>>>(count, bsum);
        scan2_kernel<<<1, 512, 0, stream>>>(bsum, bsumoff);
        scan3_kernel<<<SCAN_NB, 256, 0, stream>>>(count, bsumoff, start, cursor);
        scatter_kernel<<<NE/256, 256, 0, stream>>>(ei, cursor, sdj);
        zn_mfma_kernel<<<SCAN_NB, 256, 0, stream>>>(
            pos, zinc, rbf_c, rbf_w, zwe, zbe, zn_f);
        gather_mfma2_kernel<<<GATHER_BLOCKS, 256, 0, stream>>>(
            pos, sdj, start, rbf_c, rbf_w, w1e, b1e, pm_w2, pm_b2, agg);
    } else {
        zn_kernel<<<(NN + 255)/256, 256, 0, stream>>>(
            pos, zinc, rbf_c, rbf_w, sh_w, sh_b, zn_w, zn_b, zn_f);
        hipMemsetAsync(agg, 0, (size_t)NN * 64 * sizeof(float), stream);
        edge_kernel<<<NE/256, 256, 0, stream>>>(
            pos, ei, rbf_c, rbf_w, sh_w, sh_b, pm_w1, pm_b1, pm_w2, pm_b2, agg);
    }

    out_kernel<<<512, 256, 0, stream>>>(
        agg, zn_f, np_w, np_b, ln_g, ln_b, out);
}

// Round 5
// 759.354 us; speedup vs baseline: 1.6500x; 1.6500x over previous
//
#include <hip/hip_runtime.h>
#include <math.h>

#define N_BASIS 16
#define HIDDEN 64
#define OUT_DIM 128
#define NN 100000
#define NE 1600000
#define NPB 16
#define NTILES (NN/NPB)      // 6250
#define SCAN_NB 391          // ceil(NN/256)
#define GATHER_BLOCKS 2048

typedef __bf16 bfrag __attribute__((ext_vector_type(8)));
typedef float  ffrag __attribute__((ext_vector_type(4)));

union BF8 { bfrag v; uint4 u4; uint2 u2[2]; };

__device__ __forceinline__ unsigned pack_bf2(float lo, float hi) {
    union { float f; unsigned u; } a, b;
    a.f = lo; b.f = hi;
    unsigned ra = a.u + 0x7FFFu + ((a.u >> 16) & 1u);
    unsigned rb = b.u + 0x7FFFu + ((b.u >> 16) & 1u);
    return (ra >> 16) | (rb & 0xFFFF0000u);
}

__device__ __forceinline__ unsigned short bf16u(float x) {
    union { float f; unsigned u; } a;
    a.f = x;
    return (unsigned short)((a.u + 0x7FFFu + ((a.u >> 16) & 1u)) >> 16);
}

__device__ __forceinline__ float silu_f(float x) {          // fast: exp + rcp
    return x * __builtin_amdgcn_rcpf(1.0f + __expf(-x));
}

// Old-style feat (fallback path only)
__device__ __forceinline__ void compute_feat(
    float rx, float ry, float rz,
    const float* __restrict__ sC, const float* __restrict__ sWd,
    const float* __restrict__ sShW, const float* __restrict__ sShB,
    float* feat)
{
    float d2 = rx*rx + ry*ry + rz*rz;
    float d = fmaxf(sqrtf(d2), 1e-6f);
    float inv = 1.0f / d;
    float ux = rx*inv, uy = ry*inv, uz = rz*inv;
    #pragma unroll
    for (int m = 0; m < 16; ++m) {
        float t = d - sC[m];
        feat[m] = __expf(-fabsf(sWd[m]) * t * t);
    }
    const float c0 = 0.28209479177387814f;
    const float c1 = 0.4886025119029199f;
    const float c2 = 1.0925484305920792f;
    const float c3 = 0.31539156525252005f;
    const float c4 = 0.5462742152960396f;
    float sh0 = c0;
    float sh1 = c1*uy, sh2 = c1*uz, sh3 = c1*ux;
    float sh4 = c2*ux*uy, sh5 = c2*uy*uz;
    float sh6 = c3*(2.0f*uz*uz - ux*ux - uy*uy);
    float sh7 = c2*ux*uz, sh8 = c4*(ux*ux - uy*uy);
    #pragma unroll
    for (int m = 0; m < 16; ++m) {
        float a = sShB[m];
        a += sh0*sShW[0*16+m]; a += sh1*sShW[1*16+m]; a += sh2*sShW[2*16+m];
        a += sh3*sShW[3*16+m]; a += sh4*sShW[4*16+m]; a += sh5*sShW[5*16+m];
        a += sh6*sShW[6*16+m]; a += sh7*sShW[7*16+m]; a += sh8*sShW[8*16+m];
        feat[16+m] = a;
    }
}

// Fold sh_w/sh_b into both MLPs' first layers
__global__ __launch_bounds__(64) void prep_kernel(
    const float* __restrict__ sh_w, const float* __restrict__ sh_b,
    const float* __restrict__ w1, const float* __restrict__ b1,
    const float* __restrict__ znw, const float* __restrict__ znb,
    float* __restrict__ w1e, float* __restrict__ b1e,
    float* __restrict__ zwe, float* __restrict__ zbe)
{
    int j = threadIdx.x;
    #pragma unroll
    for (int k = 0; k < 16; ++k) {
        w1e[k*64 + j] = w1[k*64 + j];
        zwe[k*64 + j] = znw[k*64 + j];
    }
    for (int s = 0; s < 9; ++s) {
        float a = 0.0f, z = 0.0f;
        for (int m = 0; m < 16; ++m) {
            a += sh_w[s*16 + m] * w1[(16+m)*64 + j];
            z += sh_w[s*16 + m] * znw[(16+m)*64 + j];
        }
        w1e[(16+s)*64 + j] = a;
        zwe[(16+s)*64 + j] = z;
    }
    #pragma unroll
    for (int s = 25; s < 32; ++s) { w1e[s*64 + j] = 0.0f; zwe[s*64 + j] = 0.0f; }
    float bb = b1[j], zb = znb[j];
    for (int m = 0; m < 16; ++m) {
        bb += sh_b[m] * w1[(16+m)*64 + j];
        zb += sh_b[m] * znw[(16+m)*64 + j];
    }
    b1e[j] = bb;
    zbe[j] = zb;
}

// ---------------- counting-sort pipeline ----------------

__global__ __launch_bounds__(256) void hist_kernel(
    const int* __restrict__ ei, int* __restrict__ count)
{
    int e = blockIdx.x * 256 + threadIdx.x;
    atomicAdd(&count[ei[e]], 1);
}

__global__ __launch_bounds__(256) void scan1_kernel(
    int* __restrict__ count, int* __restrict__ bsum)
{
    __shared__ int s[256];
    int t = threadIdx.x;
    int i = blockIdx.x * 256 + t;
    int v = (i < NN) ? count[i] : 0;
    s[t] = v;
    __syncthreads();
    #pragma unroll
    for (int off = 1; off < 256; off <<= 1) {
        int add = (t >= off) ? s[t - off] : 0;
        __syncthreads();
        s[t] += add;
        __syncthreads();
    }
    if (i < NN) count[i] = s[t] - v;
    if (t == 255) bsum[blockIdx.x] = s[255];
}

__global__ __launch_bounds__(512) void scan2_kernel(
    const int* __restrict__ bsum, int* __restrict__ bsumoff)
{
    __shared__ int s[512];
    int t = threadIdx.x;
    int v = (t < SCAN_NB) ? bsum[t] : 0;
    s[t] = v;
    __syncthreads();
    #pragma unroll
    for (int off = 1; off < 512; off <<= 1) {
        int add = (t >= off) ? s[t - off] : 0;
        __syncthreads();
        s[t] += add;
        __syncthreads();
    }
    if (t < SCAN_NB) bsumoff[t] = s[t] - v;
}

__global__ __launch_bounds__(256) void scan3_kernel(
    const int* __restrict__ count, const int* __restrict__ bsumoff,
    int* __restrict__ start, int* __restrict__ cursor)
{
    int i = blockIdx.x * 256 + threadIdx.x;
    if (i < NN) {
        int v = count[i] + bsumoff[blockIdx.x];
        start[i] = v;
        cursor[i] = v;
    }
    if (i == 0) start[NN] = NE;
}

__global__ __launch_bounds__(256) void scatter_kernel(
    const int* __restrict__ ei, int* __restrict__ cursor,
    int* __restrict__ sdj)
{
    int e = blockIdx.x * 256 + threadIdx.x;
    int s = ei[e], d = ei[NE + e];
    int p = atomicAdd(&cursor[s], 1);
    sdj[p] = (d << 4) | (s & 15);
}

// ---------------- persistent MFMA gather, atomic-free inner loop ----------------
// Per wave, 64 sorted edges/batch:
//   FEAT built in regs -> mfma1 (4) -> silu -> h1t LDS -> mfma2 (8) -> H2^T bf16 to h2t
//   segment-reduce: accT[j][o] += S(16x64, indicator from jnb) @ H2 (8 mfma), regs only.
// Per tile: 4 waves merge accT into LDS tile with 16 atomics/lane (low contention).
__global__ __launch_bounds__(256, 2) void gather_mfma3_kernel(
    const float* __restrict__ pos,
    const int* __restrict__ sdj, const int* __restrict__ start,
    const float* __restrict__ rbf_c, const float* __restrict__ rbf_w,
    const float* __restrict__ w1e, const float* __restrict__ b1e,
    const float* __restrict__ w2, const float* __restrict__ b2,
    float* __restrict__ agg)
{
    __shared__ unsigned h1t[4][16*34];          // per-wave P scratch, row stride 136B
    __shared__ unsigned short h2t[4][64*72];    // per-wave H2^T [o][edge], stride 144B
    __shared__ unsigned short jnb[4][64];       // per-wave jn per edge (63 = invalid)
    __shared__ float tile[NPB*72];
    __shared__ float sPosL[NPB*3];
    __shared__ int sStart[NPB+1];

    int tid = threadIdx.x;
    int wave = tid >> 6, lane = tid & 63;
    int lm = lane & 15, q = lane >> 4;

    // persistent register state
    bfrag w1f[4];
    #pragma unroll
    for (int mt = 0; mt < 4; ++mt)
        #pragma unroll
        for (int kk = 0; kk < 8; ++kk)
            w1f[mt][kk] = (__bf16)w1e[(q*8 + kk)*64 + mt*16 + lm];
    bfrag w2f[2][4];
    #pragma unroll
    for (int kb = 0; kb < 2; ++kb)
        #pragma unroll
        for (int mt = 0; mt < 4; ++mt)
            #pragma unroll
            for (int kk = 0; kk < 8; ++kk)
                w2f[kb][mt][kk] = (__bf16)w2[(kb*32 + q*8 + kk)*64 + mt*16 + lm];
    ffrag b1v[4], b2v[4];
    #pragma unroll
    for (int mt = 0; mt < 4; ++mt)
        #pragma unroll
        for (int r = 0; r < 4; ++r) {
            b1v[mt][r] = b1e[mt*16 + q*4 + r];
            b2v[mt][r] = b2[mt*16 + q*4 + r];
        }
    float rc[8], rw[8];
    #pragma unroll
    for (int kk = 0; kk < 8; ++kk) {
        rc[kk] = rbf_c[(q & 1)*8 + kk];
        rw[kk] = fabsf(rbf_w[(q & 1)*8 + kk]);
    }
    unsigned* hW = &h1t[wave][0];
    unsigned short* h2W = &h2t[wave][0];
    unsigned short* jnW = &jnb[wave][0];

    const float c0 = 0.28209479177387814f;
    const float c1 = 0.4886025119029199f;
    const float c2 = 1.0925484305920792f;
    const float c3 = 0.31539156525252005f;
    const float c4 = 0.5462742152960396f;

    for (int t = blockIdx.x; t < NTILES; t += gridDim.x) {
        int nlo = t * NPB;
        if (tid < NPB + 1) sStart[tid] = start[nlo + tid];
        if (tid >= 64 && tid < 64 + NPB*3) sPosL[tid - 64] = pos[(size_t)nlo*3 + tid - 64];
        for (int i = tid; i < NPB * 72; i += 256) tile[i] = 0.0f;
        __syncthreads();

        ffrag accT[4];
        #pragma unroll
        for (int nt2 = 0; nt2 < 4; ++nt2)
            #pragma unroll
            for (int r = 0; r < 4; ++r) accT[nt2][r] = 0.0f;

        int pbeg = sStart[0], pend = sStart[NPB];
        for (int pb = pbeg + wave * 64; pb < pend; pb += 256) {
            // jn table for this 64-edge batch (63 = padded/invalid)
            {
                int pe0 = pb + lane;
                int pc0 = pe0 < pend ? pe0 : (pend - 1);
                int v0 = sdj[pc0];
                jnW[lane] = (pe0 < pend) ? (unsigned short)(v0 & 15)
                                         : (unsigned short)63;
            }
            #pragma unroll
            for (int nt = 0; nt < 4; ++nt) {
                int pe = pb + nt*16 + lm;
                int pc = pe < pend ? pe : (pend - 1);
                int v = sdj[pc];
                int d = v >> 4, jn = v & 15;
                float rx = pos[(size_t)d*3+0] - sPosL[jn*3+0];
                float ry = pos[(size_t)d*3+1] - sPosL[jn*3+1];
                float rz = pos[(size_t)d*3+2] - sPosL[jn*3+2];
                float d2 = rx*rx + ry*ry + rz*rz;
                float dd = fmaxf(sqrtf(d2), 1e-6f);
                float inv = __builtin_amdgcn_rcpf(dd);
                float ux = rx*inv, uy = ry*inv, uz = rz*inv;
                float f0,f1,f2,f3,f4,f5,f6,f7;
                if (q < 2) {
                    float t0 = dd - rc[0]; f0 = __expf(-rw[0]*t0*t0);
                    float t1 = dd - rc[1]; f1 = __expf(-rw[1]*t1*t1);
                    float t2 = dd - rc[2]; f2 = __expf(-rw[2]*t2*t2);
                    float t3 = dd - rc[3]; f3 = __expf(-rw[3]*t3*t3);
                    float t4 = dd - rc[4]; f4 = __expf(-rw[4]*t4*t4);
                    float t5 = dd - rc[5]; f5 = __expf(-rw[5]*t5*t5);
                    float t6 = dd - rc[6]; f6 = __expf(-rw[6]*t6*t6);
                    float t7 = dd - rc[7]; f7 = __expf(-rw[7]*t7*t7);
                } else if (q == 2) {
                    f0 = c0;
                    f1 = c1*uy; f2 = c1*uz; f3 = c1*ux;
                    f4 = c2*ux*uy; f5 = c2*uy*uz;
                    f6 = c3*(2.0f*uz*uz - ux*ux - uy*uy);
                    f7 = c2*ux*uz;
                } else {
                    f0 = c4*(ux*ux - uy*uy);
                    f1 = f2 = f3 = f4 = f5 = f6 = f7 = 0.0f;
                }
                BF8 bf;
                bf.u4.x = pack_bf2(f0, f1);
                bf.u4.y = pack_bf2(f2, f3);
                bf.u4.z = pack_bf2(f4, f5);
                bf.u4.w = pack_bf2(f6, f7);

                ffrag a1[4];
                #pragma unroll
                for (int mt = 0; mt < 4; ++mt) a1[mt] = b1v[mt];
                #pragma unroll
                for (int mt = 0; mt < 4; ++mt)
                    a1[mt] = __builtin_amdgcn_mfma_f32_16x16x32_bf16(w1f[mt], bf.v, a1[mt], 0, 0, 0);
                #pragma unroll
                for (int mt = 0; mt < 4; ++mt) {
                    float s0 = silu_f(a1[mt][0]);
                    float s1 = silu_f(a1[mt][1]);
                    float s2 = silu_f(a1[mt][2]);
                    float s3 = silu_f(a1[mt][3]);
                    uint2 w;
                    w.x = pack_bf2(s0, s1);
                    w.y = pack_bf2(s2, s3);
                    *(uint2*)&hW[lm*34 + mt*8 + q*2] = w;
                }
                ffrag a2[4];
                #pragma unroll
                for (int mt = 0; mt < 4; ++mt) a2[mt] = b2v[mt];
                #pragma unroll
                for (int kb = 0; kb < 2; ++kb) {
                    BF8 pf;
                    pf.u2[0] = *(const uint2*)&hW[lm*34 + kb*16 + q*4];
                    pf.u2[1] = *(const uint2*)&hW[lm*34 + kb*16 + q*4 + 2];
                    #pragma unroll
                    for (int mt = 0; mt < 4; ++mt)
                        a2[mt] = __builtin_amdgcn_mfma_f32_16x16x32_bf16(w2f[kb][mt], pf.v, a2[mt], 0, 0, 0);
                }
                // H2^T -> LDS bf16: row o = mt*16+q*4+r, col = edge nt*16+lm
                #pragma unroll
                for (int mt = 0; mt < 4; ++mt)
                    #pragma unroll
                    for (int r = 0; r < 4; ++r)
                        h2W[(mt*16 + q*4 + r)*72 + nt*16 + lm] = bf16u(a2[mt][r]);
            }
            // segment-reduce this batch: accT[j][o] += S @ H2
            #pragma unroll
            for (int kb = 0; kb < 2; ++kb) {
                uint4 jv = *(const uint4*)&jnW[kb*32 + q*8];
                unsigned lmu = (unsigned)lm;
                BF8 ind;
                {
                    unsigned a;
                    a  = ((jv.x & 0xFFFFu) == lmu) ? 0x3F80u : 0u;
                    a |= ((jv.x >> 16)     == lmu) ? 0x3F800000u : 0u;
                    ind.u4.x = a;
                    a  = ((jv.y & 0xFFFFu) == lmu) ? 0x3F80u : 0u;
                    a |= ((jv.y >> 16)     == lmu) ? 0x3F800000u : 0u;
                    ind.u4.y = a;
                    a  = ((jv.z & 0xFFFFu) == lmu) ? 0x3F80u : 0u;
                    a |= ((jv.z >> 16)     == lmu) ? 0x3F800000u : 0u;
                    ind.u4.z = a;
                    a  = ((jv.w & 0xFFFFu) == lmu) ? 0x3F80u : 0u;
                    a |= ((jv.w >> 16)     == lmu) ? 0x3F800000u : 0u;
                    ind.u4.w = a;
                }
                #pragma unroll
                for (int nt2 = 0; nt2 < 4; ++nt2) {
                    BF8 hb;
                    hb.u4 = *(const uint4*)&h2W[(nt2*16 + lm)*72 + kb*32 + q*8];
                    accT[nt2] = __builtin_amdgcn_mfma_f32_16x16x32_bf16(ind.v, hb.v, accT[nt2], 0, 0, 0);
                }
            }
        }
        // merge 4 waves into tile (lane holds j=q*4+r, o=nt2*16+lm : unique per wave)
        #pragma unroll
        for (int nt2 = 0; nt2 < 4; ++nt2)
            #pragma unroll
            for (int r = 0; r < 4; ++r)
                atomicAdd(&tile[(q*4 + r)*72 + nt2*16 + lm], accT[nt2][r]);
        __syncthreads();
        for (int i = tid; i < NPB * 64; i += 256)
            agg[(size_t)nlo * 64 + i] = tile[(i >> 6) * 72 + (i & 63)];
        __syncthreads();
    }
}

// ---------------- MFMA zinc branch (no LDS) ----------------
__global__ __launch_bounds__(256) void zn_mfma_kernel(
    const float* __restrict__ pos, const float* __restrict__ zinc,
    const float* __restrict__ rbf_c, const float* __restrict__ rbf_w,
    const float* __restrict__ zwe, const float* __restrict__ zbe,
    float* __restrict__ zn_f)
{
    int tid = threadIdx.x;
    int wave = tid >> 6, lane = tid & 63;
    int lm = lane & 15, q = lane >> 4;

    bfrag wf[4];
    #pragma unroll
    for (int mt = 0; mt < 4; ++mt)
        #pragma unroll
        for (int kk = 0; kk < 8; ++kk)
            wf[mt][kk] = (__bf16)zwe[(q*8 + kk)*64 + mt*16 + lm];
    ffrag bz[4];
    #pragma unroll
    for (int mt = 0; mt < 4; ++mt)
        #pragma unroll
        for (int r = 0; r < 4; ++r)
            bz[mt][r] = zbe[mt*16 + q*4 + r];
    float rc[8], rw[8];
    #pragma unroll
    for (int kk = 0; kk < 8; ++kk) {
        rc[kk] = rbf_c[(q & 1)*8 + kk];
        rw[kk] = fabsf(rbf_w[(q & 1)*8 + kk]);
    }
    float zx = zinc[0], zy = zinc[1], zz = zinc[2];

    const float c0 = 0.28209479177387814f;
    const float c1 = 0.4886025119029199f;
    const float c2 = 1.0925484305920792f;
    const float c3 = 0.31539156525252005f;
    const float c4 = 0.5462742152960396f;

    int n0 = (blockIdx.x * 4 + wave) * 64;
    #pragma unroll
    for (int nt = 0; nt < 4; ++nt) {
        int n = n0 + nt*16 + lm;
        int nc = n < NN ? n : NN - 1;
        float rx = pos[(size_t)nc*3+0] - zx;
        float ry = pos[(size_t)nc*3+1] - zy;
        float rz = pos[(size_t)nc*3+2] - zz;
        float d2 = rx*rx + ry*ry + rz*rz;
        float dd = fmaxf(sqrtf(d2), 1e-6f);
        float inv = __builtin_amdgcn_rcpf(dd);
        float ux = rx*inv, uy = ry*inv, uz = rz*inv;
        float f0,f1,f2,f3,f4,f5,f6,f7;
        if (q < 2) {
            float t0 = dd - rc[0]; f0 = __expf(-rw[0]*t0*t0);
            float t1 = dd - rc[1]; f1 = __expf(-rw[1]*t1*t1);
            float t2 = dd - rc[2]; f2 = __expf(-rw[2]*t2*t2);
            float t3 = dd - rc[3]; f3 = __expf(-rw[3]*t3*t3);
            float t4 = dd - rc[4]; f4 = __expf(-rw[4]*t4*t4);
            float t5 = dd - rc[5]; f5 = __expf(-rw[5]*t5*t5);
            float t6 = dd - rc[6]; f6 = __expf(-rw[6]*t6*t6);
            float t7 = dd - rc[7]; f7 = __expf(-rw[7]*t7*t7);
        } else if (q == 2) {
            f0 = c0;
            f1 = c1*uy; f2 = c1*uz; f3 = c1*ux;
            f4 = c2*ux*uy; f5 = c2*uy*uz;
            f6 = c3*(2.0f*uz*uz - ux*ux - uy*uy);
            f7 = c2*ux*uz;
        } else {
            f0 = c4*(ux*ux - uy*uy);
            f1 = f2 = f3 = f4 = f5 = f6 = f7 = 0.0f;
        }
        BF8 bf;
        bf.u4.x = pack_bf2(f0, f1);
        bf.u4.y = pack_bf2(f2, f3);
        bf.u4.z = pack_bf2(f4, f5);
        bf.u4.w = pack_bf2(f6, f7);

        ffrag a[4];
        #pragma unroll
        for (int mt = 0; mt < 4; ++mt) a[mt] = bz[mt];
        #pragma unroll
        for (int mt = 0; mt < 4; ++mt)
            a[mt] = __builtin_amdgcn_mfma_f32_16x16x32_bf16(wf[mt], bf.v, a[mt], 0, 0, 0);
        if (n < NN) {
            #pragma unroll
            for (int mt = 0; mt < 4; ++mt) {
                float4 vv;
                vv.x = silu_f(a[mt][0]);
                vv.y = silu_f(a[mt][1]);
                vv.z = silu_f(a[mt][2]);
                vv.w = silu_f(a[mt][3]);
                *(float4*)&zn_f[(size_t)n*64 + mt*16 + q*4] = vv;
            }
        }
    }
}

// ---------------- fallback kernels (round-1 path) ----------------

__global__ __launch_bounds__(256) void edge_kernel(
    const float* __restrict__ pos, const int* __restrict__ edge_index,
    const float* __restrict__ rbf_c, const float* __restrict__ rbf_w,
    const float* __restrict__ sh_w, const float* __restrict__ sh_b,
    const float* __restrict__ w1, const float* __restrict__ b1,
    const float* __restrict__ w2, const float* __restrict__ b2,
    float* __restrict__ agg)
{
    __shared__ float sW1[2048];
    __shared__ float sW2[4096];
    __shared__ float sShW[144], sShB[16], sC[16], sWd[16], sB1[64], sB2[64];
    int tid = threadIdx.x;
    for (int i = tid; i < 2048; i += 256) sW1[i] = w1[i];
    for (int i = tid; i < 4096; i += 256) sW2[i] = w2[i];
    if (tid < 144) sShW[tid] = sh_w[tid];
    if (tid < 16) { sShB[tid] = sh_b[tid]; sC[tid] = rbf_c[tid]; sWd[tid] = rbf_w[tid]; }
    if (tid < 64) sB1[tid] = b1[tid];
    if (tid >= 64 && tid < 128) sB2[tid-64] = b2[tid-64];
    __syncthreads();

    int e = blockIdx.x * 256 + tid;
    int s   = edge_index[e];
    int dst = edge_index[NE + e];
    const float* ps = pos + 3*(size_t)s;
    const float* pd = pos + 3*(size_t)dst;
    float rx = pd[0]-ps[0], ry = pd[1]-ps[1], rz = pd[2]-ps[2];
    float feat[32];
    compute_feat(rx, ry, rz, sC, sWd, sShW, sShB, feat);

    float h2[64];
    #pragma unroll
    for (int o = 0; o < 64; ++o) h2[o] = sB2[o];

    #pragma unroll 1
    for (int jc = 0; jc < 8; ++jc) {
        float h1c[8];
        #pragma unroll
        for (int jj = 0; jj < 8; ++jj) h1c[jj] = sB1[jc*8+jj];
        #pragma unroll
        for (int k = 0; k < 32; ++k) {
            float f = feat[k];
            #pragma unroll
            for (int jj = 0; jj < 8; ++jj) h1c[jj] += f * sW1[k*64 + jc*8 + jj];
        }
        #pragma unroll
        for (int jj = 0; jj < 8; ++jj) h1c[jj] = silu_f(h1c[jj]);
        #pragma unroll
        for (int jj = 0; jj < 8; ++jj) {
            float v = h1c[jj];
            #pragma unroll
            for (int o = 0; o < 64; ++o) h2[o] += v * sW2[(jc*8+jj)*64 + o];
        }
    }
    size_t base = (size_t)s * 64;
    #pragma unroll
    for (int o = 0; o < 64; ++o)
        unsafeAtomicAdd(&agg[base + o], h2[o]);
}

__global__ __launch_bounds__(256) void zn_kernel(
    const float* __restrict__ pos, const float* __restrict__ zinc_pos,
    const float* __restrict__ rbf_c, const float* __restrict__ rbf_w,
    const float* __restrict__ sh_w, const float* __restrict__ sh_b,
    const float* __restrict__ zn_w, const float* __restrict__ zn_b,
    float* __restrict__ zn_f)
{
    __shared__ float sW[2048];
    __shared__ float sShW[144], sShB[16], sC[16], sWd[16], sB[64];
    int tid = threadIdx.x;
    for (int i = tid; i < 2048; i += 256) sW[i] = zn_w[i];
    if (tid < 144) sShW[tid] = sh_w[tid];
    if (tid < 16) { sShB[tid] = sh_b[tid]; sC[tid] = rbf_c[tid]; sWd[tid] = rbf_w[tid]; }
    if (tid < 64) sB[tid] = zn_b[tid];
    __syncthreads();
    int n = blockIdx.x * 256 + tid;
    if (n >= NN) return;
    float rx = pos[n*3+0] - zinc_pos[0];
    float ry = pos[n*3+1] - zinc_pos[1];
    float rz = pos[n*3+2] - zinc_pos[2];
    float feat[32];
    compute_feat(rx, ry, rz, sC, sWd, sShW, sShB, feat);
    #pragma unroll 1
    for (int jc = 0; jc < 8; ++jc) {
        float h[8];
        #pragma unroll
        for (int jj = 0; jj < 8; ++jj) h[jj] = sB[jc*8+jj];
        #pragma unroll
        for (int k = 0; k < 32; ++k) {
            float f = feat[k];
            #pragma unroll
            for (int jj = 0; jj < 8; ++jj) h[jj] += f * sW[k*64 + jc*8 + jj];
        }
        #pragma unroll
        for (int jj = 0; jj < 8; ++jj)
            zn_f[(size_t)n*64 + jc*8 + jj] = silu_f(h[jj]);
    }
}

// ---------------- output projection + LN + SiLU ----------------

__global__ __launch_bounds__(256) void out_kernel(
    const float* __restrict__ agg, const float* __restrict__ zn_f,
    const float* __restrict__ np_w, const float* __restrict__ np_b,
    const float* __restrict__ ln_g, const float* __restrict__ ln_b,
    float* __restrict__ out)
{
    __shared__ float sX[128*36];
    __shared__ float sH[32*130];
    __shared__ float sMu[32], sVar[32];
    int tid = threadIdx.x;
    int o = tid & 127;
    int nb = (tid >> 7) * 16;
    float bias = np_b[o];
    float g = ln_g[o], bta = ln_b[o];

    for (int n0 = blockIdx.x * 32; n0 < NN; n0 += gridDim.x * 32) {
        for (int i = tid; i < 4096; i += 256) {
            int n = i >> 7, k = i & 127;
            float v = (k < 64) ? agg[(size_t)(n0+n)*64 + k]
                               : zn_f[(size_t)(n0+n)*64 + (k-64)];
            sX[k*36 + n] = v;
        }
        __syncthreads();
        float acc[16];
        #pragma unroll
        for (int i = 0; i < 16; ++i) acc[i] = bias;
        #pragma unroll 4
        for (int k = 0; k < 128; ++k) {
            float w = np_w[k*128 + o];
            const float* xr = &sX[k*36 + nb];
            #pragma unroll
            for (int i = 0; i < 16; ++i) acc[i] += w * xr[i];
        }
        #pragma unroll
        for (int i = 0; i < 16; ++i) sH[(nb+i)*130 + o] = acc[i];
        __syncthreads();
        if (tid < 32) {
            float s = 0.0f, sq = 0.0f;
            for (int oo = 0; oo < 128; ++oo) {
                float v = sH[tid*130 + oo];
                s += v; sq += v*v;
            }
            float mu = s * (1.0f/128.0f);
            sMu[tid] = mu;
            sVar[tid] = sq * (1.0f/128.0f) - mu*mu;
        }
        __syncthreads();
        #pragma unroll
        for (int i = 0; i < 16; ++i) {
            int n = nb + i;
            float y = (acc[i] - sMu[n]) * rsqrtf(sVar[n] + 1e-5f) * g + bta;
            out[(size_t)(n0+n)*128 + o] = silu_f(y);
        }
        __syncthreads();
    }
}

extern "C" void kernel_launch(void* const* d_in, const int* in_sizes, int n_in,
                              void* d_out, int out_size, void* d_ws, size_t ws_size,
                              hipStream_t stream) {
    const float* pos   = (const float*)d_in[0];
    const float* zinc  = (const float*)d_in[1];
    const int*   ei    = (const int*)  d_in[2];
    const float* rbf_c = (const float*)d_in[3];
    const float* rbf_w = (const float*)d_in[4];
    const float* sh_w  = (const float*)d_in[5];
    const float* sh_b  = (const float*)d_in[6];
    const float* pm_w1 = (const float*)d_in[7];
    const float* pm_b1 = (const float*)d_in[8];
    const float* pm_w2 = (const float*)d_in[9];
    const float* pm_b2 = (const float*)d_in[10];
    const float* zn_w  = (const float*)d_in[11];
    const float* zn_b  = (const float*)d_in[12];
    const float* np_w  = (const float*)d_in[13];
    const float* np_b  = (const float*)d_in[14];
    const float* ln_g  = (const float*)d_in[15];
    const float* ln_b  = (const float*)d_in[16];
    float* out  = (float*)d_out;

    float* agg  = (float*)d_ws;                        // NN*64 f
    float* zn_f = agg + (size_t)NN * 64;               // NN*64 f
    int* count   = (int*)(zn_f + (size_t)NN * 64);     // NN
    int* start   = count + NN;                         // NN+1
    int* cursor  = start + NN + 1;                     // NN
    int* bsum    = cursor + NN;                        // 512
    int* bsumoff = bsum + 512;                         // 512
    int* sdj     = bsumoff + 512;                      // NE
    float* w1e   = (float*)(sdj + NE);                 // 2048
    float* b1e   = w1e + 2048;                         // 64
    float* zwe   = b1e + 64;                           // 2048
    float* zbe   = zwe + 2048;                         // 64
    size_t needed = (size_t)((char*)(zbe + 64) - (char*)d_ws);

    if (ws_size >= needed) {
        prep_kernel<<<1, 64, 0, stream>>>(sh_w, sh_b, pm_w1, pm_b1, zn_w, zn_b,
                                          w1e, b1e, zwe, zbe);
        hipMemsetAsync(count, 0, NN * sizeof(int), stream);
        hist_kernel<<<NE/256, 256, 0, stream>>>(ei, count);
        scan1_kernel<<<SCAN_NB, 256, 0, stream>>>(count, bsum);
        scan2_kernel<<<1, 512, 0, stream>>>(bsum, bsumoff);
        scan3_kernel<<<SCAN_NB, 256, 0, stream>>>(count, bsumoff, start, cursor);
        scatter_kernel<<<NE/256, 256, 0, stream>>>(ei, cursor, sdj);
        zn_mfma_kernel<<<SCAN_NB, 256, 0, stream>>>(
            pos, zinc, rbf_c, rbf_w, zwe, zbe, zn_f);
        gather_mfma3_kernel<<<GATHER_BLOCKS, 256, 0, stream>>>(
            pos, sdj, start, rbf_c, rbf_w, w1e, b1e, pm_w2, pm_b2, agg);
    } else {
        zn_kernel<<<(NN + 255)/256, 256, 0, stream>>>(
            pos, zinc, rbf_c, rbf_w, sh_w, sh_b, zn_w, zn_b, zn_f);
        hipMemsetAsync(agg, 0, (size_t)NN * 64 * sizeof(float), stream);
        edge_kernel<<<NE/256, 256, 0, stream>>>(
            pos, ei, rbf_c, rbf_w, sh_w, sh_b, pm_w1, pm_b1, pm_w2, pm_b2, agg);
    }

    out_kernel<<<512, 256, 0, stream>>>(
        agg, zn_f, np_w, np_b, ln_g, ln_b, out);
}

// Round 6
// 343.212 us; speedup vs baseline: 3.6507x; 2.2125x over previous
//
#include <hip/hip_runtime.h>
#include <math.h>

#define N_BASIS 16
#define HIDDEN 64
#define OUT_DIM 128
#define NN 100000
#define NE 1600000
#define NPB 16
#define NTILES (NN/NPB)      // 6250
#define SCAN_NB 391          // ceil(NN/256)
#define GATHER_BLOCKS 768    // 3 blocks/CU co-resident, ~2 tiles/wave

typedef __bf16 bfrag __attribute__((ext_vector_type(8)));
typedef float  ffrag __attribute__((ext_vector_type(4)));

union BF8 { bfrag v; uint4 u4; uint2 u2[2]; };

__device__ __forceinline__ unsigned pack_bf2(float lo, float hi) {
    union { float f; unsigned u; } a, b;
    a.f = lo; b.f = hi;
    unsigned ra = a.u + 0x7FFFu + ((a.u >> 16) & 1u);
    unsigned rb = b.u + 0x7FFFu + ((b.u >> 16) & 1u);
    return (ra >> 16) | (rb & 0xFFFF0000u);
}

__device__ __forceinline__ unsigned short bf16u(float x) {
    union { float f; unsigned u; } a;
    a.f = x;
    return (unsigned short)((a.u + 0x7FFFu + ((a.u >> 16) & 1u)) >> 16);
}

__device__ __forceinline__ float bf16f(unsigned short h) {
    union { unsigned u; float f; } a;
    a.u = ((unsigned)h) << 16;
    return a.f;
}

__device__ __forceinline__ float silu_f(float x) {
    return x * __builtin_amdgcn_rcpf(1.0f + __expf(-x));
}

// Build this lane's 8 feat components (q selects which 8) as a bf16 B-frag slice
__device__ __forceinline__ void feat_frag(
    int q, float rx, float ry, float rz,
    const float* rc, const float* rw, BF8& bf)
{
    float d2 = rx*rx + ry*ry + rz*rz;
    float dd = fmaxf(sqrtf(d2), 1e-6f);
    float inv = __builtin_amdgcn_rcpf(dd);
    float ux = rx*inv, uy = ry*inv, uz = rz*inv;
    const float c0 = 0.28209479177387814f;
    const float c1 = 0.4886025119029199f;
    const float c2 = 1.0925484305920792f;
    const float c3 = 0.31539156525252005f;
    const float c4 = 0.5462742152960396f;
    float f0,f1,f2,f3,f4,f5,f6,f7;
    if (q < 2) {
        float t0 = dd - rc[0]; f0 = __expf(-rw[0]*t0*t0);
        float t1 = dd - rc[1]; f1 = __expf(-rw[1]*t1*t1);
        float t2 = dd - rc[2]; f2 = __expf(-rw[2]*t2*t2);
        float t3 = dd - rc[3]; f3 = __expf(-rw[3]*t3*t3);
        float t4 = dd - rc[4]; f4 = __expf(-rw[4]*t4*t4);
        float t5 = dd - rc[5]; f5 = __expf(-rw[5]*t5*t5);
        float t6 = dd - rc[6]; f6 = __expf(-rw[6]*t6*t6);
        float t7 = dd - rc[7]; f7 = __expf(-rw[7]*t7*t7);
    } else if (q == 2) {
        f0 = c0;
        f1 = c1*uy; f2 = c1*uz; f3 = c1*ux;
        f4 = c2*ux*uy; f5 = c2*uy*uz;
        f6 = c3*(2.0f*uz*uz - ux*ux - uy*uy);
        f7 = c2*ux*uz;
    } else {
        f0 = c4*(ux*ux - uy*uy);
        f1 = f2 = f3 = f4 = f5 = f6 = f7 = 0.0f;
    }
    bf.u4.x = pack_bf2(f0, f1);
    bf.u4.y = pack_bf2(f2, f3);
    bf.u4.z = pack_bf2(f4, f5);
    bf.u4.w = pack_bf2(f6, f7);
}

// Old-style feat (fallback path only)
__device__ __forceinline__ void compute_feat(
    float rx, float ry, float rz,
    const float* __restrict__ sC, const float* __restrict__ sWd,
    const float* __restrict__ sShW, const float* __restrict__ sShB,
    float* feat)
{
    float d2 = rx*rx + ry*ry + rz*rz;
    float d = fmaxf(sqrtf(d2), 1e-6f);
    float inv = 1.0f / d;
    float ux = rx*inv, uy = ry*inv, uz = rz*inv;
    #pragma unroll
    for (int m = 0; m < 16; ++m) {
        float t = d - sC[m];
        feat[m] = __expf(-fabsf(sWd[m]) * t * t);
    }
    const float c0 = 0.28209479177387814f;
    const float c1 = 0.4886025119029199f;
    const float c2 = 1.0925484305920792f;
    const float c3 = 0.31539156525252005f;
    const float c4 = 0.5462742152960396f;
    float sh0 = c0;
    float sh1 = c1*uy, sh2 = c1*uz, sh3 = c1*ux;
    float sh4 = c2*ux*uy, sh5 = c2*uy*uz;
    float sh6 = c3*(2.0f*uz*uz - ux*ux - uy*uy);
    float sh7 = c2*ux*uz, sh8 = c4*(ux*ux - uy*uy);
    #pragma unroll
    for (int m = 0; m < 16; ++m) {
        float a = sShB[m];
        a += sh0*sShW[0*16+m]; a += sh1*sShW[1*16+m]; a += sh2*sShW[2*16+m];
        a += sh3*sShW[3*16+m]; a += sh4*sShW[4*16+m]; a += sh5*sShW[5*16+m];
        a += sh6*sShW[6*16+m]; a += sh7*sShW[7*16+m]; a += sh8*sShW[8*16+m];
        feat[16+m] = a;
    }
}

// Fold sh_w/sh_b into both MLPs' first layers
__global__ __launch_bounds__(64) void prep_kernel(
    const float* __restrict__ sh_w, const float* __restrict__ sh_b,
    const float* __restrict__ w1, const float* __restrict__ b1,
    const float* __restrict__ znw, const float* __restrict__ znb,
    float* __restrict__ w1e, float* __restrict__ b1e,
    float* __restrict__ zwe, float* __restrict__ zbe)
{
    int j = threadIdx.x;
    #pragma unroll
    for (int k = 0; k < 16; ++k) {
        w1e[k*64 + j] = w1[k*64 + j];
        zwe[k*64 + j] = znw[k*64 + j];
    }
    for (int s = 0; s < 9; ++s) {
        float a = 0.0f, z = 0.0f;
        for (int m = 0; m < 16; ++m) {
            a += sh_w[s*16 + m] * w1[(16+m)*64 + j];
            z += sh_w[s*16 + m] * znw[(16+m)*64 + j];
        }
        w1e[(16+s)*64 + j] = a;
        zwe[(16+s)*64 + j] = z;
    }
    #pragma unroll
    for (int s = 25; s < 32; ++s) { w1e[s*64 + j] = 0.0f; zwe[s*64 + j] = 0.0f; }
    float bb = b1[j], zb = znb[j];
    for (int m = 0; m < 16; ++m) {
        bb += sh_b[m] * w1[(16+m)*64 + j];
        zb += sh_b[m] * znw[(16+m)*64 + j];
    }
    b1e[j] = bb;
    zbe[j] = zb;
}

// ---------------- counting-sort pipeline (rank-based, scatter atomic-free) ----------------

__global__ __launch_bounds__(256) void hist_rank_kernel(
    const int* __restrict__ ei, int* __restrict__ count, int* __restrict__ rank)
{
    int e = blockIdx.x * 256 + threadIdx.x;
    rank[e] = atomicAdd(&count[ei[e]], 1);
}

__global__ __launch_bounds__(256) void scan1_kernel(
    int* __restrict__ count, int* __restrict__ bsum)
{
    __shared__ int s[256];
    int t = threadIdx.x;
    int i = blockIdx.x * 256 + t;
    int v = (i < NN) ? count[i] : 0;
    s[t] = v;
    __syncthreads();
    #pragma unroll
    for (int off = 1; off < 256; off <<= 1) {
        int add = (t >= off) ? s[t - off] : 0;
        __syncthreads();
        s[t] += add;
        __syncthreads();
    }
    if (i < NN) count[i] = s[t] - v;
    if (t == 255) bsum[blockIdx.x] = s[255];
}

__global__ __launch_bounds__(512) void scan2_kernel(
    const int* __restrict__ bsum, int* __restrict__ bsumoff)
{
    __shared__ int s[512];
    int t = threadIdx.x;
    int v = (t < SCAN_NB) ? bsum[t] : 0;
    s[t] = v;
    __syncthreads();
    #pragma unroll
    for (int off = 1; off < 512; off <<= 1) {
        int add = (t >= off) ? s[t - off] : 0;
        __syncthreads();
        s[t] += add;
        __syncthreads();
    }
    if (t < SCAN_NB) bsumoff[t] = s[t] - v;
}

__global__ __launch_bounds__(256) void scan3_kernel(
    const int* __restrict__ count, const int* __restrict__ bsumoff,
    int* __restrict__ start)
{
    int i = blockIdx.x * 256 + threadIdx.x;
    if (i < NN) start[i] = count[i] + bsumoff[blockIdx.x];
    if (i == 0) start[NN] = NE;
}

__global__ __launch_bounds__(256) void scatter2_kernel(
    const int* __restrict__ ei, const int* __restrict__ rank,
    const int* __restrict__ start, int* __restrict__ sdj)
{
    int e = blockIdx.x * 256 + threadIdx.x;
    int s = ei[e], d = ei[NE + e];
    int p = start[s] + rank[e];
    sdj[p] = (d << 4) | (s & 15);
}

// ---------------- wave-per-tile MFMA gather: no barriers, no atomics ----------------
// agg_tile = (sum_batches S@P) @ W2 + deg*b2 ; SP accumulated in regs, W2 applied once.
__global__ __launch_bounds__(256, 2) void gather_mfma4_kernel(
    const float* __restrict__ pos,
    const int* __restrict__ sdj, const int* __restrict__ start,
    const float* __restrict__ rbf_c, const float* __restrict__ rbf_w,
    const float* __restrict__ w1e, const float* __restrict__ b1e,
    const float* __restrict__ w2, const float* __restrict__ b2,
    float* __restrict__ agg)
{
    // per-wave private: P^T [j 0..63][edge 0..63] bf16, row stride 72 shorts (144B, 16B-mult)
    __shared__ __align__(16) unsigned short pT[4][64*72];
    __shared__ unsigned short jnb[4][64];
    __shared__ float posb[4][52];

    int tid = threadIdx.x;
    int wave = tid >> 6, lane = tid & 63;
    int lm = lane & 15, q = lane >> 4;

    bfrag w1f[4];
    #pragma unroll
    for (int mt = 0; mt < 4; ++mt)
        #pragma unroll
        for (int kk = 0; kk < 8; ++kk)
            w1f[mt][kk] = (__bf16)w1e[(q*8 + kk)*64 + mt*16 + lm];
    bfrag w2f[2][4];
    #pragma unroll
    for (int kb = 0; kb < 2; ++kb)
        #pragma unroll
        for (int mt = 0; mt < 4; ++mt)
            #pragma unroll
            for (int kk = 0; kk < 8; ++kk)
                w2f[kb][mt][kk] = (__bf16)w2[(kb*32 + q*8 + kk)*64 + mt*16 + lm];
    ffrag b1v[4];
    #pragma unroll
    for (int mt = 0; mt < 4; ++mt)
        #pragma unroll
        for (int r = 0; r < 4; ++r)
            b1v[mt][r] = b1e[mt*16 + q*4 + r];
    float b2s[4];
    #pragma unroll
    for (int mt = 0; mt < 4; ++mt) b2s[mt] = b2[mt*16 + lm];
    float rc[8], rw[8];
    #pragma unroll
    for (int kk = 0; kk < 8; ++kk) {
        rc[kk] = rbf_c[(q & 1)*8 + kk];
        rw[kk] = fabsf(rbf_w[(q & 1)*8 + kk]);
    }
    unsigned short* pW  = &pT[wave][0];
    unsigned short* jnW = &jnb[wave][0];
    float* posW = &posb[wave][0];

    for (int t = blockIdx.x * 4 + wave; t < NTILES; t += gridDim.x * 4) {
        int nlo = t * NPB;
        int stv = (lane < 17) ? start[nlo + lane] : 0;
        int pbeg = __shfl(stv, 0);
        int pend = __shfl(stv, 16);
        float dg[4];
        #pragma unroll
        for (int r = 0; r < 4; ++r)
            dg[r] = (float)(__shfl(stv, q*4 + r + 1) - __shfl(stv, q*4 + r));
        if (lane < 48) posW[lane] = pos[(size_t)nlo*3 + lane];

        ffrag accSP[4];
        #pragma unroll
        for (int nt2 = 0; nt2 < 4; ++nt2)
            #pragma unroll
            for (int r = 0; r < 4; ++r) accSP[nt2][r] = 0.0f;

        for (int pb = pbeg; pb < pend; pb += 64) {
            {
                int pe0 = pb + lane;
                int pc0 = pe0 < pend ? pe0 : (pend - 1);
                int v0 = sdj[pc0];
                jnW[lane] = (pe0 < pend) ? (unsigned short)(v0 & 15)
                                         : (unsigned short)63;
            }
            #pragma unroll
            for (int nt = 0; nt < 4; ++nt) {
                int pe = pb + nt*16 + lm;
                int pc = pe < pend ? pe : (pend - 1);
                int v = sdj[pc];
                int d = v >> 4, jn = v & 15;
                float rx = pos[(size_t)d*3+0] - posW[jn*3+0];
                float ry = pos[(size_t)d*3+1] - posW[jn*3+1];
                float rz = pos[(size_t)d*3+2] - posW[jn*3+2];
                BF8 bf;
                feat_frag(q, rx, ry, rz, rc, rw, bf);
                ffrag a1[4];
                #pragma unroll
                for (int mt = 0; mt < 4; ++mt) a1[mt] = b1v[mt];
                #pragma unroll
                for (int mt = 0; mt < 4; ++mt)
                    a1[mt] = __builtin_amdgcn_mfma_f32_16x16x32_bf16(w1f[mt], bf.v, a1[mt], 0, 0, 0);
                // silu -> P^T[j][edge]
                #pragma unroll
                for (int mt = 0; mt < 4; ++mt)
                    #pragma unroll
                    for (int r = 0; r < 4; ++r)
                        pW[(mt*16 + q*4 + r)*72 + nt*16 + lm] = bf16u(silu_f(a1[mt][r]));
            }
            // SP += S @ P  (S = indicator A-frag from jnW)
            #pragma unroll
            for (int kb = 0; kb < 2; ++kb) {
                uint4 jv = *(const uint4*)&jnW[kb*32 + q*8];
                unsigned lmu = (unsigned)lm;
                BF8 ind;
                {
                    unsigned a;
                    a  = ((jv.x & 0xFFFFu) == lmu) ? 0x3F80u : 0u;
                    a |= ((jv.x >> 16)     == lmu) ? 0x3F800000u : 0u;
                    ind.u4.x = a;
                    a  = ((jv.y & 0xFFFFu) == lmu) ? 0x3F80u : 0u;
                    a |= ((jv.y >> 16)     == lmu) ? 0x3F800000u : 0u;
                    ind.u4.y = a;
                    a  = ((jv.z & 0xFFFFu) == lmu) ? 0x3F80u : 0u;
                    a |= ((jv.z >> 16)     == lmu) ? 0x3F800000u : 0u;
                    ind.u4.z = a;
                    a  = ((jv.w & 0xFFFFu) == lmu) ? 0x3F80u : 0u;
                    a |= ((jv.w >> 16)     == lmu) ? 0x3F800000u : 0u;
                    ind.u4.w = a;
                }
                #pragma unroll
                for (int nt2 = 0; nt2 < 4; ++nt2) {
                    BF8 pb8;
                    pb8.u4 = *(const uint4*)&pW[(nt2*16 + lm)*72 + kb*32 + q*8];
                    accSP[nt2] = __builtin_amdgcn_mfma_f32_16x16x32_bf16(ind.v, pb8.v, accSP[nt2], 0, 0, 0);
                }
            }
        }
        // SP -> LDS as hi/lo bf16 (rows 0..15 hi, 16..31 lo), reuse pT region
        #pragma unroll
        for (int nt2 = 0; nt2 < 4; ++nt2)
            #pragma unroll
            for (int r = 0; r < 4; ++r) {
                float vv = accSP[nt2][r];
                unsigned short h = bf16u(vv);
                unsigned short l = bf16u(vv - bf16f(h));
                pW[(q*4 + r)*72 + nt2*16 + lm] = h;
                pW[(16 + q*4 + r)*72 + nt2*16 + lm] = l;
            }
        BF8 hiA[2], loA[2];
        #pragma unroll
        for (int kb = 0; kb < 2; ++kb) {
            hiA[kb].u4 = *(const uint4*)&pW[lm*72 + kb*32 + q*8];
            loA[kb].u4 = *(const uint4*)&pW[(16 + lm)*72 + kb*32 + q*8];
        }
        // agg_tile = SP @ W2 + deg*b2
        #pragma unroll
        for (int mt = 0; mt < 4; ++mt) {
            ffrag c;
            #pragma unroll
            for (int r = 0; r < 4; ++r) c[r] = b2s[mt] * dg[r];
            #pragma unroll
            for (int kb = 0; kb < 2; ++kb) {
                c = __builtin_amdgcn_mfma_f32_16x16x32_bf16(hiA[kb].v, w2f[kb][mt], c, 0, 0, 0);
                c = __builtin_amdgcn_mfma_f32_16x16x32_bf16(loA[kb].v, w2f[kb][mt], c, 0, 0, 0);
            }
            #pragma unroll
            for (int r = 0; r < 4; ++r)
                agg[(size_t)(nlo + q*4 + r)*64 + mt*16 + lm] = c[r];
        }
    }
}

// ---------------- fused epilogue: zn(MFMA) + np projection(MFMA) + LN + SiLU ----------------
// Block = 2 node-groups of 16; each group served by 2 waves (o-halves 0-63 / 64-127).
__global__ __launch_bounds__(256, 2) void out2_kernel(
    const float* __restrict__ agg, const float* __restrict__ pos,
    const float* __restrict__ zinc,
    const float* __restrict__ rbf_c, const float* __restrict__ rbf_w,
    const float* __restrict__ zwe, const float* __restrict__ zbe,
    const float* __restrict__ np_w, const float* __restrict__ np_b,
    const float* __restrict__ ln_g, const float* __restrict__ ln_b,
    float* __restrict__ out)
{
    __shared__ __align__(16) unsigned short XZ[4][16*72];  // per-wave zn half of X
    __shared__ float red[2][2][16][2];

    int tid = threadIdx.x;
    int wave = tid >> 6, lane = tid & 63;
    int lm = lane & 15, q = lane >> 4;
    int grp = wave >> 1, half = wave & 1;
    int n0g = blockIdx.x * 32 + grp * 16;
    int ob = half * 64;

    bfrag npf[4][4];
    #pragma unroll
    for (int kb = 0; kb < 4; ++kb)
        #pragma unroll
        for (int ot = 0; ot < 4; ++ot)
            #pragma unroll
            for (int kk = 0; kk < 8; ++kk)
                npf[kb][ot][kk] = (__bf16)np_w[(kb*32 + q*8 + kk)*128 + ob + ot*16 + lm];
    bfrag zf[4];
    #pragma unroll
    for (int mt = 0; mt < 4; ++mt)
        #pragma unroll
        for (int kk = 0; kk < 8; ++kk)
            zf[mt][kk] = (__bf16)zwe[(q*8 + kk)*64 + mt*16 + lm];
    ffrag zb[4];
    #pragma unroll
    for (int mt = 0; mt < 4; ++mt)
        #pragma unroll
        for (int r = 0; r < 4; ++r)
            zb[mt][r] = zbe[mt*16 + q*4 + r];
    float npb_s[4], lg[4], lb[4];
    #pragma unroll
    for (int ot = 0; ot < 4; ++ot) {
        int o = ob + ot*16 + lm;
        npb_s[ot] = np_b[o];
        lg[ot] = ln_g[o];
        lb[ot] = ln_b[o];
    }
    float rc[8], rw[8];
    #pragma unroll
    for (int kk = 0; kk < 8; ++kk) {
        rc[kk] = rbf_c[(q & 1)*8 + kk];
        rw[kk] = fabsf(rbf_w[(q & 1)*8 + kk]);
    }
    float zx = zinc[0], zy = zinc[1], zz = zinc[2];
    unsigned short* xz = &XZ[wave][0];

    // zn half of X: B-frag per node (n = n0g+lm), 4 MFMAs
    {
        int n = n0g + lm;
        float rx = pos[(size_t)n*3+0] - zx;
        float ry = pos[(size_t)n*3+1] - zy;
        float rz = pos[(size_t)n*3+2] - zz;
        BF8 bf;
        feat_frag(q, rx, ry, rz, rc, rw, bf);
        ffrag a[4];
        #pragma unroll
        for (int mt = 0; mt < 4; ++mt) a[mt] = zb[mt];
        #pragma unroll
        for (int mt = 0; mt < 4; ++mt)
            a[mt] = __builtin_amdgcn_mfma_f32_16x16x32_bf16(zf[mt], bf.v, a[mt], 0, 0, 0);
        #pragma unroll
        for (int mt = 0; mt < 4; ++mt) {
            unsigned w0 = pack_bf2(silu_f(a[mt][0]), silu_f(a[mt][1]));
            unsigned w1 = pack_bf2(silu_f(a[mt][2]), silu_f(a[mt][3]));
            *(unsigned*)&xz[lm*72 + mt*16 + q*4]     = w0;
            *(unsigned*)&xz[lm*72 + mt*16 + q*4 + 2] = w1;
        }
    }
    // h = [agg, zn] @ np_w + np_b  (agg half hi/lo-compensated)
    ffrag c[4];
    #pragma unroll
    for (int ot = 0; ot < 4; ++ot)
        #pragma unroll
        for (int r = 0; r < 4; ++r) c[ot][r] = npb_s[ot];
    #pragma unroll
    for (int kb = 0; kb < 2; ++kb) {
        const float* ap = &agg[(size_t)(n0g + lm)*64 + kb*32 + q*8];
        float4 v0 = *(const float4*)ap;
        float4 v1 = *(const float4*)(ap + 4);
        float vv[8] = {v0.x, v0.y, v0.z, v0.w, v1.x, v1.y, v1.z, v1.w};
        unsigned short hs[8], ls[8];
        #pragma unroll
        for (int kk = 0; kk < 8; ++kk) {
            hs[kk] = bf16u(vv[kk]);
            ls[kk] = bf16u(vv[kk] - bf16f(hs[kk]));
        }
        BF8 hi, lo;
        hi.u4.x = (unsigned)hs[0] | ((unsigned)hs[1] << 16);
        hi.u4.y = (unsigned)hs[2] | ((unsigned)hs[3] << 16);
        hi.u4.z = (unsigned)hs[4] | ((unsigned)hs[5] << 16);
        hi.u4.w = (unsigned)hs[6] | ((unsigned)hs[7] << 16);
        lo.u4.x = (unsigned)ls[0] | ((unsigned)ls[1] << 16);
        lo.u4.y = (unsigned)ls[2] | ((unsigned)ls[3] << 16);
        lo.u4.z = (unsigned)ls[4] | ((unsigned)ls[5] << 16);
        lo.u4.w = (unsigned)ls[6] | ((unsigned)ls[7] << 16);
        #pragma unroll
        for (int ot = 0; ot < 4; ++ot) {
            c[ot] = __builtin_amdgcn_mfma_f32_16x16x32_bf16(hi.v, npf[kb][ot], c[ot], 0, 0, 0);
            c[ot] = __builtin_amdgcn_mfma_f32_16x16x32_bf16(lo.v, npf[kb][ot], c[ot], 0, 0, 0);
        }
    }
    #pragma unroll
    for (int kb = 0; kb < 2; ++kb) {
        BF8 za;
        za.u4 = *(const uint4*)&xz[lm*72 + kb*32 + q*8];
        #pragma unroll
        for (int ot = 0; ot < 4; ++ot)
            c[ot] = __builtin_amdgcn_mfma_f32_16x16x32_bf16(za.v, npf[2+kb][ot], c[ot], 0, 0, 0);
    }
    // LN stats: per node r, partial over 4 ot, butterfly over lm
    float s[4], sq[4];
    #pragma unroll
    for (int r = 0; r < 4; ++r) {
        s[r]  = c[0][r] + c[1][r] + c[2][r] + c[3][r];
        sq[r] = c[0][r]*c[0][r] + c[1][r]*c[1][r] + c[2][r]*c[2][r] + c[3][r]*c[3][r];
    }
    #pragma unroll
    for (int off = 1; off < 16; off <<= 1) {
        #pragma unroll
        for (int r = 0; r < 4; ++r) {
            s[r]  += __shfl_xor(s[r], off);
            sq[r] += __shfl_xor(sq[r], off);
        }
    }
    if (lm == 0) {
        #pragma unroll
        for (int r = 0; r < 4; ++r) {
            red[grp][half][q*4 + r][0] = s[r];
            red[grp][half][q*4 + r][1] = sq[r];
        }
    }
    __syncthreads();
    #pragma unroll
    for (int r = 0; r < 4; ++r) {
        int j = q*4 + r;
        float ts = red[grp][0][j][0] + red[grp][1][j][0];
        float tq = red[grp][0][j][1] + red[grp][1][j][1];
        float mu = ts * (1.0f/128.0f);
        float var = tq * (1.0f/128.0f) - mu*mu;
        float rs = rsqrtf(var + 1e-5f);
        #pragma unroll
        for (int ot = 0; ot < 4; ++ot) {
            float y = (c[ot][r] - mu) * rs * lg[ot] + lb[ot];
            out[(size_t)(n0g + j)*128 + ob + ot*16 + lm] = silu_f(y);
        }
    }
}

// ---------------- fallback kernels (round-1 path) ----------------

__global__ __launch_bounds__(256) void edge_kernel(
    const float* __restrict__ pos, const int* __restrict__ edge_index,
    const float* __restrict__ rbf_c, const float* __restrict__ rbf_w,
    const float* __restrict__ sh_w, const float* __restrict__ sh_b,
    const float* __restrict__ w1, const float* __restrict__ b1,
    const float* __restrict__ w2, const float* __restrict__ b2,
    float* __restrict__ agg)
{
    __shared__ float sW1[2048];
    __shared__ float sW2[4096];
    __shared__ float sShW[144], sShB[16], sC[16], sWd[16], sB1[64], sB2[64];
    int tid = threadIdx.x;
    for (int i = tid; i < 2048; i += 256) sW1[i] = w1[i];
    for (int i = tid; i < 4096; i += 256) sW2[i] = w2[i];
    if (tid < 144) sShW[tid] = sh_w[tid];
    if (tid < 16) { sShB[tid] = sh_b[tid]; sC[tid] = rbf_c[tid]; sWd[tid] = rbf_w[tid]; }
    if (tid < 64) sB1[tid] = b1[tid];
    if (tid >= 64 && tid < 128) sB2[tid-64] = b2[tid-64];
    __syncthreads();

    int e = blockIdx.x * 256 + tid;
    int s   = edge_index[e];
    int dst = edge_index[NE + e];
    const float* ps = pos + 3*(size_t)s;
    const float* pd = pos + 3*(size_t)dst;
    float rx = pd[0]-ps[0], ry = pd[1]-ps[1], rz = pd[2]-ps[2];
    float feat[32];
    compute_feat(rx, ry, rz, sC, sWd, sShW, sShB, feat);

    float h2[64];
    #pragma unroll
    for (int o = 0; o < 64; ++o) h2[o] = sB2[o];

    #pragma unroll 1
    for (int jc = 0; jc < 8; ++jc) {
        float h1c[8];
        #pragma unroll
        for (int jj = 0; jj < 8; ++jj) h1c[jj] = sB1[jc*8+jj];
        #pragma unroll
        for (int k = 0; k < 32; ++k) {
            float f = feat[k];
            #pragma unroll
            for (int jj = 0; jj < 8; ++jj) h1c[jj] += f * sW1[k*64 + jc*8 + jj];
        }
        #pragma unroll
        for (int jj = 0; jj < 8; ++jj) h1c[jj] = silu_f(h1c[jj]);
        #pragma unroll
        for (int jj = 0; jj < 8; ++jj) {
            float v = h1c[jj];
            #pragma unroll
            for (int o = 0; o < 64; ++o) h2[o] += v * sW2[(jc*8+jj)*64 + o];
        }
    }
    size_t base = (size_t)s * 64;
    #pragma unroll
    for (int o = 0; o < 64; ++o)
        unsafeAtomicAdd(&agg[base + o], h2[o]);
}

__global__ __launch_bounds__(256) void zn_kernel(
    const float* __restrict__ pos, const float* __restrict__ zinc_pos,
    const float* __restrict__ rbf_c, const float* __restrict__ rbf_w,
    const float* __restrict__ sh_w, const float* __restrict__ sh_b,
    const float* __restrict__ zn_w, const float* __restrict__ zn_b,
    float* __restrict__ zn_f)
{
    __shared__ float sW[2048];
    __shared__ float sShW[144], sShB[16], sC[16], sWd[16], sB[64];
    int tid = threadIdx.x;
    for (int i = tid; i < 2048; i += 256) sW[i] = zn_w[i];
    if (tid < 144) sShW[tid] = sh_w[tid];
    if (tid < 16) { sShB[tid] = sh_b[tid]; sC[tid] = rbf_c[tid]; sWd[tid] = rbf_w[tid]; }
    if (tid < 64) sB[tid] = zn_b[tid];
    __syncthreads();
    int n = blockIdx.x * 256 + tid;
    if (n >= NN) return;
    float rx = pos[n*3+0] - zinc_pos[0];
    float ry = pos[n*3+1] - zinc_pos[1];
    float rz = pos[n*3+2] - zinc_pos[2];
    float feat[32];
    compute_feat(rx, ry, rz, sC, sWd, sShW, sShB, feat);
    #pragma unroll 1
    for (int jc = 0; jc < 8; ++jc) {
        float h[8];
        #pragma unroll
        for (int jj = 0; jj < 8; ++jj) h[jj] = sB[jc*8+jj];
        #pragma unroll
        for (int k = 0; k < 32; ++k) {
            float f = feat[k];
            #pragma unroll
            for (int jj = 0; jj < 8; ++jj) h[jj] += f * sW[k*64 + jc*8 + jj];
        }
        #pragma unroll
        for (int jj = 0; jj < 8; ++jj)
            zn_f[(size_t)n*64 + jc*8 + jj] = silu_f(h[jj]);
    }
}

__global__ __launch_bounds__(256) void out_kernel(
    const float* __restrict__ agg, const float* __restrict__ zn_f,
    const float* __restrict__ np_w, const float* __restrict__ np_b,
    const float* __restrict__ ln_g, const float* __restrict__ ln_b,
    float* __restrict__ out)
{
    __shared__ float sX[128*36];
    __shared__ float sH[32*130];
    __shared__ float sMu[32], sVar[32];
    int tid = threadIdx.x;
    int o = tid & 127;
    int nb = (tid >> 7) * 16;
    float bias = np_b[o];
    float g = ln_g[o], bta = ln_b[o];

    for (int n0 = blockIdx.x * 32; n0 < NN; n0 += gridDim.x * 32) {
        for (int i = tid; i < 4096; i += 256) {
            int n = i >> 7, k = i & 127;
            float v = (k < 64) ? agg[(size_t)(n0+n)*64 + k]
                               : zn_f[(size_t)(n0+n)*64 + (k-64)];
            sX[k*36 + n] = v;
        }
        __syncthreads();
        float acc[16];
        #pragma unroll
        for (int i = 0; i < 16; ++i) acc[i] = bias;
        #pragma unroll 4
        for (int k = 0; k < 128; ++k) {
            float w = np_w[k*128 + o];
            const float* xr = &sX[k*36 + nb];
            #pragma unroll
            for (int i = 0; i < 16; ++i) acc[i] += w * xr[i];
        }
        #pragma unroll
        for (int i = 0; i < 16; ++i) sH[(nb+i)*130 + o] = acc[i];
        __syncthreads();
        if (tid < 32) {
            float s = 0.0f, sq2 = 0.0f;
            for (int oo = 0; oo < 128; ++oo) {
                float v = sH[tid*130 + oo];
                s += v; sq2 += v*v;
            }
            float mu = s * (1.0f/128.0f);
            sMu[tid] = mu;
            sVar[tid] = sq2 * (1.0f/128.0f) - mu*mu;
        }
        __syncthreads();
        #pragma unroll
        for (int i = 0; i < 16; ++i) {
            int n = nb + i;
            float y = (acc[i] - sMu[n]) * rsqrtf(sVar[n] + 1e-5f) * g + bta;
            out[(size_t)(n0+n)*128 + o] = silu_f(y);
        }
        __syncthreads();
    }
}

extern "C" void kernel_launch(void* const* d_in, const int* in_sizes, int n_in,
                              void* d_out, int out_size, void* d_ws, size_t ws_size,
                              hipStream_t stream) {
    const float* pos   = (const float*)d_in[0];
    const float* zinc  = (const float*)d_in[1];
    const int*   ei    = (const int*)  d_in[2];
    const float* rbf_c = (const float*)d_in[3];
    const float* rbf_w = (const float*)d_in[4];
    const float* sh_w  = (const float*)d_in[5];
    const float* sh_b  = (const float*)d_in[6];
    const float* pm_w1 = (const float*)d_in[7];
    const float* pm_b1 = (const float*)d_in[8];
    const float* pm_w2 = (const float*)d_in[9];
    const float* pm_b2 = (const float*)d_in[10];
    const float* zn_w  = (const float*)d_in[11];
    const float* zn_b  = (const float*)d_in[12];
    const float* np_w  = (const float*)d_in[13];
    const float* np_b  = (const float*)d_in[14];
    const float* ln_g  = (const float*)d_in[15];
    const float* ln_b  = (const float*)d_in[16];
    float* out  = (float*)d_out;

    // fused-path layout (zn_f not needed)
    float* agg   = (float*)d_ws;                       // NN*64 f
    int* count   = (int*)(agg + (size_t)NN * 64);      // NN
    int* start   = count + NN;                         // NN+1
    int* rank    = start + NN + 1;                     // NE
    int* sdj     = rank + NE;                          // NE
    int* bsum    = sdj + NE;                           // 512
    int* bsumoff = bsum + 512;                         // 512
    float* w1e   = (float*)(bsumoff + 512);            // 2048
    float* b1e   = w1e + 2048;                         // 64
    float* zwe   = b1e + 64;                           // 2048
    float* zbe   = zwe + 2048;                         // 64
    size_t needed = (size_t)((char*)(zbe + 64) - (char*)d_ws);

    if (ws_size >= needed) {
        prep_kernel<<<1, 64, 0, stream>>>(sh_w, sh_b, pm_w1, pm_b1, zn_w, zn_b,
                                          w1e, b1e, zwe, zbe);
        hipMemsetAsync(count, 0, NN * sizeof(int), stream);
        hist_rank_kernel<<<NE/256, 256, 0, stream>>>(ei, count, rank);
        scan1_kernel<<<SCAN_NB, 256, 0, stream>>>(count, bsum);
        scan2_kernel<<<1, 512, 0, stream>>>(bsum, bsumoff);
        scan3_kernel<<<SCAN_NB, 256, 0, stream>>>(count, bsumoff, start);
        scatter2_kernel<<<NE/256, 256, 0, stream>>>(ei, rank, start, sdj);
        gather_mfma4_kernel<<<GATHER_BLOCKS, 256, 0, stream>>>(
            pos, sdj, start, rbf_c, rbf_w, w1e, b1e, pm_w2, pm_b2, agg);
        out2_kernel<<<NN/32, 256, 0, stream>>>(
            agg, pos, zinc, rbf_c, rbf_w, zwe, zbe, np_w, np_b, ln_g, ln_b, out);
    } else {
        // fallback: round-1 atomic path (zn_f overlaps sort arrays; unused there)
        float* zn_f = (float*)count;
        zn_kernel<<<(NN + 255)/256, 256, 0, stream>>>(
            pos, zinc, rbf_c, rbf_w, sh_w, sh_b, zn_w, zn_b, zn_f);
        hipMemsetAsync(agg, 0, (size_t)NN * 64 * sizeof(float), stream);
        edge_kernel<<<NE/256, 256, 0, stream>>>(
            pos, ei, rbf_c, rbf_w, sh_w, sh_b, pm_w1, pm_b1, pm_w2, pm_b2, agg);
        out_kernel<<<512, 256, 0, stream>>>(
            agg, zn_f, np_w, np_b, ln_g, ln_b, out);
    }
}

// Round 7
// 313.534 us; speedup vs baseline: 3.9963x; 1.0947x over previous
//
#include <hip/hip_runtime.h>
#include <math.h>

#define N_BASIS 16
#define HIDDEN 64
#define OUT_DIM 128
#define NN 100000
#define NE 1600000
#define NPB 16
#define NTILES (NN/NPB)      // 6250
#define SCAN_NB 391          // ceil(NN/256)
#define GATHER_BLOCKS 1563   // 1 tile per wave (6252 waves >= 6250 tiles)

typedef __bf16 bfrag __attribute__((ext_vector_type(8)));
typedef float  ffrag __attribute__((ext_vector_type(4)));

union BF8 { bfrag v; uint4 u4; uint2 u2[2]; };

// pack two floats to bf16 pair via v_perm (round-half-up; ulp-level same as RNE)
__device__ __forceinline__ unsigned pack_bf2(float lo, float hi) {
    union { float f; unsigned u; } a, b;
    a.f = lo; b.f = hi;
    return __builtin_amdgcn_perm(b.u + 0x8000u, a.u + 0x8000u, 0x07060302u);
}

__device__ __forceinline__ unsigned short bf16u(float x) {
    union { float f; unsigned u; } a;
    a.f = x;
    return (unsigned short)((a.u + 0x8000u) >> 16);
}

__device__ __forceinline__ float bf16f(unsigned short h) {
    union { unsigned u; float f; } a;
    a.u = ((unsigned)h) << 16;
    return a.f;
}

__device__ __forceinline__ float silu_f(float x) {
    return x * __builtin_amdgcn_rcpf(1.0f + __expf(-x));
}

// Build this lane's 8 feat components (q selects which 8) as a bf16 B-frag slice
__device__ __forceinline__ void feat_frag(
    int q, float rx, float ry, float rz,
    const float* rc, const float* rw, BF8& bf)
{
    float d2 = rx*rx + ry*ry + rz*rz;
    float dd = fmaxf(sqrtf(d2), 1e-6f);
    float inv = __builtin_amdgcn_rcpf(dd);
    float ux = rx*inv, uy = ry*inv, uz = rz*inv;
    const float c0 = 0.28209479177387814f;
    const float c1 = 0.4886025119029199f;
    const float c2 = 1.0925484305920792f;
    const float c3 = 0.31539156525252005f;
    const float c4 = 0.5462742152960396f;
    float f0,f1,f2,f3,f4,f5,f6,f7;
    if (q < 2) {
        float t0 = dd - rc[0]; f0 = __expf(-rw[0]*t0*t0);
        float t1 = dd - rc[1]; f1 = __expf(-rw[1]*t1*t1);
        float t2 = dd - rc[2]; f2 = __expf(-rw[2]*t2*t2);
        float t3 = dd - rc[3]; f3 = __expf(-rw[3]*t3*t3);
        float t4 = dd - rc[4]; f4 = __expf(-rw[4]*t4*t4);
        float t5 = dd - rc[5]; f5 = __expf(-rw[5]*t5*t5);
        float t6 = dd - rc[6]; f6 = __expf(-rw[6]*t6*t6);
        float t7 = dd - rc[7]; f7 = __expf(-rw[7]*t7*t7);
    } else if (q == 2) {
        f0 = c0;
        f1 = c1*uy; f2 = c1*uz; f3 = c1*ux;
        f4 = c2*ux*uy; f5 = c2*uy*uz;
        f6 = c3*(2.0f*uz*uz - ux*ux - uy*uy);
        f7 = c2*ux*uz;
    } else {
        f0 = c4*(ux*ux - uy*uy);
        f1 = f2 = f3 = f4 = f5 = f6 = f7 = 0.0f;
    }
    bf.u4.x = pack_bf2(f0, f1);
    bf.u4.y = pack_bf2(f2, f3);
    bf.u4.z = pack_bf2(f4, f5);
    bf.u4.w = pack_bf2(f6, f7);
}

// Old-style feat (fallback path only)
__device__ __forceinline__ void compute_feat(
    float rx, float ry, float rz,
    const float* __restrict__ sC, const float* __restrict__ sWd,
    const float* __restrict__ sShW, const float* __restrict__ sShB,
    float* feat)
{
    float d2 = rx*rx + ry*ry + rz*rz;
    float d = fmaxf(sqrtf(d2), 1e-6f);
    float inv = 1.0f / d;
    float ux = rx*inv, uy = ry*inv, uz = rz*inv;
    #pragma unroll
    for (int m = 0; m < 16; ++m) {
        float t = d - sC[m];
        feat[m] = __expf(-fabsf(sWd[m]) * t * t);
    }
    const float c0 = 0.28209479177387814f;
    const float c1 = 0.4886025119029199f;
    const float c2 = 1.0925484305920792f;
    const float c3 = 0.31539156525252005f;
    const float c4 = 0.5462742152960396f;
    float sh0 = c0;
    float sh1 = c1*uy, sh2 = c1*uz, sh3 = c1*ux;
    float sh4 = c2*ux*uy, sh5 = c2*uy*uz;
    float sh6 = c3*(2.0f*uz*uz - ux*ux - uy*uy);
    float sh7 = c2*ux*uz, sh8 = c4*(ux*ux - uy*uy);
    #pragma unroll
    for (int m = 0; m < 16; ++m) {
        float a = sShB[m];
        a += sh0*sShW[0*16+m]; a += sh1*sShW[1*16+m]; a += sh2*sShW[2*16+m];
        a += sh3*sShW[3*16+m]; a += sh4*sShW[4*16+m]; a += sh5*sShW[5*16+m];
        a += sh6*sShW[6*16+m]; a += sh7*sShW[7*16+m]; a += sh8*sShW[8*16+m];
        feat[16+m] = a;
    }
}

// Fold sh_w/sh_b into both MLPs' first layers + zero the histogram (391 blocks)
__global__ __launch_bounds__(256) void prep_kernel(
    const float* __restrict__ sh_w, const float* __restrict__ sh_b,
    const float* __restrict__ w1, const float* __restrict__ b1,
    const float* __restrict__ znw, const float* __restrict__ znb,
    float* __restrict__ w1e, float* __restrict__ b1e,
    float* __restrict__ zwe, float* __restrict__ zbe,
    int* __restrict__ count)
{
    int i = blockIdx.x * 256 + threadIdx.x;
    if (i < NN) count[i] = 0;
    if (blockIdx.x != 0 || threadIdx.x >= 64) return;
    int j = threadIdx.x;
    #pragma unroll
    for (int k = 0; k < 16; ++k) {
        w1e[k*64 + j] = w1[k*64 + j];
        zwe[k*64 + j] = znw[k*64 + j];
    }
    for (int s = 0; s < 9; ++s) {
        float a = 0.0f, z = 0.0f;
        for (int m = 0; m < 16; ++m) {
            a += sh_w[s*16 + m] * w1[(16+m)*64 + j];
            z += sh_w[s*16 + m] * znw[(16+m)*64 + j];
        }
        w1e[(16+s)*64 + j] = a;
        zwe[(16+s)*64 + j] = z;
    }
    #pragma unroll
    for (int s = 25; s < 32; ++s) { w1e[s*64 + j] = 0.0f; zwe[s*64 + j] = 0.0f; }
    float bb = b1[j], zb = znb[j];
    for (int m = 0; m < 16; ++m) {
        bb += sh_b[m] * w1[(16+m)*64 + j];
        zb += sh_b[m] * znw[(16+m)*64 + j];
    }
    b1e[j] = bb;
    zbe[j] = zb;
}

// ---------------- counting-sort pipeline ----------------

__global__ __launch_bounds__(256) void hist_rank_kernel(
    const int* __restrict__ ei, int* __restrict__ count, int* __restrict__ rank)
{
    int e = blockIdx.x * 256 + threadIdx.x;
    rank[e] = atomicAdd(&count[ei[e]], 1);
}

__global__ __launch_bounds__(256) void scan1_kernel(
    int* __restrict__ count, int* __restrict__ bsum)
{
    __shared__ int s[256];
    int t = threadIdx.x;
    int i = blockIdx.x * 256 + t;
    int v = (i < NN) ? count[i] : 0;
    s[t] = v;
    __syncthreads();
    #pragma unroll
    for (int off = 1; off < 256; off <<= 1) {
        int add = (t >= off) ? s[t - off] : 0;
        __syncthreads();
        s[t] += add;
        __syncthreads();
    }
    if (i < NN) count[i] = s[t] - v;
    if (t == 255) bsum[blockIdx.x] = s[255];
}

// each block redundantly reduces its bsum prefix, then writes start[]
__global__ __launch_bounds__(256) void scan23_kernel(
    const int* __restrict__ count, const int* __restrict__ bsum,
    int* __restrict__ start)
{
    __shared__ int sred[256];
    int t = threadIdx.x;
    int part = 0;
    for (int k = t; k < blockIdx.x; k += 256) part += bsum[k];
    sred[t] = part;
    __syncthreads();
    #pragma unroll
    for (int off = 128; off > 0; off >>= 1) {
        if (t < off) sred[t] += sred[t + off];
        __syncthreads();
    }
    int off0 = sred[0];
    int i = blockIdx.x * 256 + t;
    if (i < NN) start[i] = count[i] + off0;
    if (i == 0) start[NN] = NE;
}

__global__ __launch_bounds__(256) void scatter2_kernel(
    const int* __restrict__ ei, const int* __restrict__ rank,
    const int* __restrict__ start, int* __restrict__ sdj)
{
    int e = blockIdx.x * 256 + threadIdx.x;
    int s = ei[e], d = ei[NE + e];
    int p = start[s] + rank[e];
    sdj[p] = (d << 4) | (s & 15);
}

// ---------------- wave-per-tile MFMA gather: no barriers, no atomics ----------------
// agg_tile = (sum_batches S@P) @ W2 + deg*b2 ; SP accumulated in regs, W2 applied once.
// One tile per wave (GATHER_BLOCKS*4 >= NTILES) for max co-residency.
__global__ __launch_bounds__(256, 2) void gather_mfma5_kernel(
    const float* __restrict__ pos,
    const int* __restrict__ sdj, const int* __restrict__ start,
    const float* __restrict__ rbf_c, const float* __restrict__ rbf_w,
    const float* __restrict__ w1e, const float* __restrict__ b1e,
    const float* __restrict__ w2, const float* __restrict__ b2,
    float* __restrict__ agg)
{
    __shared__ __align__(16) unsigned short pT[4][64*72];  // per-wave P^T [j][edge]
    __shared__ unsigned short jnb[4][64];
    __shared__ float posb[4][52];

    int tid = threadIdx.x;
    int wave = tid >> 6, lane = tid & 63;
    int lm = lane & 15, q = lane >> 4;

    bfrag w1f[4];
    #pragma unroll
    for (int mt = 0; mt < 4; ++mt)
        #pragma unroll
        for (int kk = 0; kk < 8; ++kk)
            w1f[mt][kk] = (__bf16)w1e[(q*8 + kk)*64 + mt*16 + lm];
    bfrag w2f[2][4];
    #pragma unroll
    for (int kb = 0; kb < 2; ++kb)
        #pragma unroll
        for (int mt = 0; mt < 4; ++mt)
            #pragma unroll
            for (int kk = 0; kk < 8; ++kk)
                w2f[kb][mt][kk] = (__bf16)w2[(kb*32 + q*8 + kk)*64 + mt*16 + lm];
    ffrag b1v[4];
    #pragma unroll
    for (int mt = 0; mt < 4; ++mt)
        #pragma unroll
        for (int r = 0; r < 4; ++r)
            b1v[mt][r] = b1e[mt*16 + q*4 + r];
    float b2s[4];
    #pragma unroll
    for (int mt = 0; mt < 4; ++mt) b2s[mt] = b2[mt*16 + lm];
    float rc[8], rw[8];
    #pragma unroll
    for (int kk = 0; kk < 8; ++kk) {
        rc[kk] = rbf_c[(q & 1)*8 + kk];
        rw[kk] = fabsf(rbf_w[(q & 1)*8 + kk]);
    }
    unsigned short* pW  = &pT[wave][0];
    unsigned short* jnW = &jnb[wave][0];
    float* posW = &posb[wave][0];

    for (int t = blockIdx.x * 4 + wave; t < NTILES; t += gridDim.x * 4) {
        int nlo = t * NPB;
        int stv = (lane < 17) ? start[nlo + lane] : 0;
        int pbeg = __shfl(stv, 0);
        int pend = __shfl(stv, 16);
        float dg[4];
        #pragma unroll
        for (int r = 0; r < 4; ++r)
            dg[r] = (float)(__shfl(stv, q*4 + r + 1) - __shfl(stv, q*4 + r));
        if (lane < 48) posW[lane] = pos[(size_t)nlo*3 + lane];

        ffrag accSP[4];
        #pragma unroll
        for (int nt2 = 0; nt2 < 4; ++nt2)
            #pragma unroll
            for (int r = 0; r < 4; ++r) accSP[nt2][r] = 0.0f;

        for (int pb = pbeg; pb < pend; pb += 64) {
            int pe0 = pb + lane;
            int pc0 = pe0 < pend ? pe0 : (pend - 1);
            int v0 = sdj[pc0];
            jnW[lane] = (pe0 < pend) ? (unsigned short)(v0 & 15)
                                     : (unsigned short)63;
            #pragma unroll
            for (int nt = 0; nt < 4; ++nt) {
                int v = __shfl(v0, nt*16 + lm);     // sdj value of edge nt*16+lm
                int d = v >> 4, jn = v & 15;
                float rx = pos[(size_t)d*3+0] - posW[jn*3+0];
                float ry = pos[(size_t)d*3+1] - posW[jn*3+1];
                float rz = pos[(size_t)d*3+2] - posW[jn*3+2];
                BF8 bf;
                feat_frag(q, rx, ry, rz, rc, rw, bf);
                ffrag a1[4];
                #pragma unroll
                for (int mt = 0; mt < 4; ++mt) a1[mt] = b1v[mt];
                #pragma unroll
                for (int mt = 0; mt < 4; ++mt)
                    a1[mt] = __builtin_amdgcn_mfma_f32_16x16x32_bf16(w1f[mt], bf.v, a1[mt], 0, 0, 0);
                // silu -> P^T[j][edge]
                #pragma unroll
                for (int mt = 0; mt < 4; ++mt)
                    #pragma unroll
                    for (int r = 0; r < 4; ++r)
                        pW[(mt*16 + q*4 + r)*72 + nt*16 + lm] = bf16u(silu_f(a1[mt][r]));
            }
            // SP += S @ P  (S = indicator A-frag from jnW)
            #pragma unroll
            for (int kb = 0; kb < 2; ++kb) {
                uint4 jv = *(const uint4*)&jnW[kb*32 + q*8];
                unsigned lmu = (unsigned)lm;
                BF8 ind;
                {
                    unsigned a;
                    a  = ((jv.x & 0xFFFFu) == lmu) ? 0x3F80u : 0u;
                    a |= ((jv.x >> 16)     == lmu) ? 0x3F800000u : 0u;
                    ind.u4.x = a;
                    a  = ((jv.y & 0xFFFFu) == lmu) ? 0x3F80u : 0u;
                    a |= ((jv.y >> 16)     == lmu) ? 0x3F800000u : 0u;
                    ind.u4.y = a;
                    a  = ((jv.z & 0xFFFFu) == lmu) ? 0x3F80u : 0u;
                    a |= ((jv.z >> 16)     == lmu) ? 0x3F800000u : 0u;
                    ind.u4.z = a;
                    a  = ((jv.w & 0xFFFFu) == lmu) ? 0x3F80u : 0u;
                    a |= ((jv.w >> 16)     == lmu) ? 0x3F800000u : 0u;
                    ind.u4.w = a;
                }
                #pragma unroll
                for (int nt2 = 0; nt2 < 4; ++nt2) {
                    BF8 pb8;
                    pb8.u4 = *(const uint4*)&pW[(nt2*16 + lm)*72 + kb*32 + q*8];
                    accSP[nt2] = __builtin_amdgcn_mfma_f32_16x16x32_bf16(ind.v, pb8.v, accSP[nt2], 0, 0, 0);
                }
            }
        }
        // SP -> LDS as hi/lo bf16 (rows 0..15 hi, 16..31 lo), reuse pT region
        #pragma unroll
        for (int nt2 = 0; nt2 < 4; ++nt2)
            #pragma unroll
            for (int r = 0; r < 4; ++r) {
                float vv = accSP[nt2][r];
                unsigned short h = bf16u(vv);
                unsigned short l = bf16u(vv - bf16f(h));
                pW[(q*4 + r)*72 + nt2*16 + lm] = h;
                pW[(16 + q*4 + r)*72 + nt2*16 + lm] = l;
            }
        BF8 hiA[2], loA[2];
        #pragma unroll
        for (int kb = 0; kb < 2; ++kb) {
            hiA[kb].u4 = *(const uint4*)&pW[lm*72 + kb*32 + q*8];
            loA[kb].u4 = *(const uint4*)&pW[(16 + lm)*72 + kb*32 + q*8];
        }
        // agg_tile = SP @ W2 + deg*b2
        #pragma unroll
        for (int mt = 0; mt < 4; ++mt) {
            ffrag c;
            #pragma unroll
            for (int r = 0; r < 4; ++r) c[r] = b2s[mt] * dg[r];
            #pragma unroll
            for (int kb = 0; kb < 2; ++kb) {
                c = __builtin_amdgcn_mfma_f32_16x16x32_bf16(hiA[kb].v, w2f[kb][mt], c, 0, 0, 0);
                c = __builtin_amdgcn_mfma_f32_16x16x32_bf16(loA[kb].v, w2f[kb][mt], c, 0, 0, 0);
            }
            #pragma unroll
            for (int r = 0; r < 4; ++r)
                agg[(size_t)(nlo + q*4 + r)*64 + mt*16 + lm] = c[r];
        }
    }
}

// ---------------- fused epilogue (persistent): zn(MFMA) + np(MFMA) + LN + SiLU ----------------
__global__ __launch_bounds__(256, 2) void out2_kernel(
    const float* __restrict__ agg, const float* __restrict__ pos,
    const float* __restrict__ zinc,
    const float* __restrict__ rbf_c, const float* __restrict__ rbf_w,
    const float* __restrict__ zwe, const float* __restrict__ zbe,
    const float* __restrict__ np_w, const float* __restrict__ np_b,
    const float* __restrict__ ln_g, const float* __restrict__ ln_b,
    float* __restrict__ out)
{
    __shared__ __align__(16) unsigned short XZ[4][16*72];  // per-wave zn half of X
    __shared__ float red[2][2][16][2];

    int tid = threadIdx.x;
    int wave = tid >> 6, lane = tid & 63;
    int lm = lane & 15, q = lane >> 4;
    int grp = wave >> 1, half = wave & 1;
    int ob = half * 64;

    bfrag npf[4][4];
    #pragma unroll
    for (int kb = 0; kb < 4; ++kb)
        #pragma unroll
        for (int ot = 0; ot < 4; ++ot)
            #pragma unroll
            for (int kk = 0; kk < 8; ++kk)
                npf[kb][ot][kk] = (__bf16)np_w[(kb*32 + q*8 + kk)*128 + ob + ot*16 + lm];
    bfrag zf[4];
    #pragma unroll
    for (int mt = 0; mt < 4; ++mt)
        #pragma unroll
        for (int kk = 0; kk < 8; ++kk)
            zf[mt][kk] = (__bf16)zwe[(q*8 + kk)*64 + mt*16 + lm];
    ffrag zb[4];
    #pragma unroll
    for (int mt = 0; mt < 4; ++mt)
        #pragma unroll
        for (int r = 0; r < 4; ++r)
            zb[mt][r] = zbe[mt*16 + q*4 + r];
    float npb_s[4], lg[4], lb[4];
    #pragma unroll
    for (int ot = 0; ot < 4; ++ot) {
        int o = ob + ot*16 + lm;
        npb_s[ot] = np_b[o];
        lg[ot] = ln_g[o];
        lb[ot] = ln_b[o];
    }
    float rc[8], rw[8];
    #pragma unroll
    for (int kk = 0; kk < 8; ++kk) {
        rc[kk] = rbf_c[(q & 1)*8 + kk];
        rw[kk] = fabsf(rbf_w[(q & 1)*8 + kk]);
    }
    float zx = zinc[0], zy = zinc[1], zz = zinc[2];
    unsigned short* xz = &XZ[wave][0];

    for (int g0 = blockIdx.x; g0 < NN/32; g0 += gridDim.x) {
        int n0g = g0 * 32 + grp * 16;
        // zn half of X: B-frag per node (n = n0g+lm), 4 MFMAs
        {
            int n = n0g + lm;
            float rx = pos[(size_t)n*3+0] - zx;
            float ry = pos[(size_t)n*3+1] - zy;
            float rz = pos[(size_t)n*3+2] - zz;
            BF8 bf;
            feat_frag(q, rx, ry, rz, rc, rw, bf);
            ffrag a[4];
            #pragma unroll
            for (int mt = 0; mt < 4; ++mt) a[mt] = zb[mt];
            #pragma unroll
            for (int mt = 0; mt < 4; ++mt)
                a[mt] = __builtin_amdgcn_mfma_f32_16x16x32_bf16(zf[mt], bf.v, a[mt], 0, 0, 0);
            #pragma unroll
            for (int mt = 0; mt < 4; ++mt) {
                unsigned w0 = pack_bf2(silu_f(a[mt][0]), silu_f(a[mt][1]));
                unsigned w1 = pack_bf2(silu_f(a[mt][2]), silu_f(a[mt][3]));
                *(unsigned*)&xz[lm*72 + mt*16 + q*4]     = w0;
                *(unsigned*)&xz[lm*72 + mt*16 + q*4 + 2] = w1;
            }
        }
        // h = [agg, zn] @ np_w + np_b  (agg half hi/lo-compensated)
        ffrag c[4];
        #pragma unroll
        for (int ot = 0; ot < 4; ++ot)
            #pragma unroll
            for (int r = 0; r < 4; ++r) c[ot][r] = npb_s[ot];
        #pragma unroll
        for (int kb = 0; kb < 2; ++kb) {
            const float* ap = &agg[(size_t)(n0g + lm)*64 + kb*32 + q*8];
            float4 v0 = *(const float4*)ap;
            float4 v1 = *(const float4*)(ap + 4);
            float vv[8] = {v0.x, v0.y, v0.z, v0.w, v1.x, v1.y, v1.z, v1.w};
            unsigned short hs[8], ls[8];
            #pragma unroll
            for (int kk = 0; kk < 8; ++kk) {
                hs[kk] = bf16u(vv[kk]);
                ls[kk] = bf16u(vv[kk] - bf16f(hs[kk]));
            }
            BF8 hi, lo;
            hi.u4.x = (unsigned)hs[0] | ((unsigned)hs[1] << 16);
            hi.u4.y = (unsigned)hs[2] | ((unsigned)hs[3] << 16);
            hi.u4.z = (unsigned)hs[4] | ((unsigned)hs[5] << 16);
            hi.u4.w = (unsigned)hs[6] | ((unsigned)hs[7] << 16);
            lo.u4.x = (unsigned)ls[0] | ((unsigned)ls[1] << 16);
            lo.u4.y = (unsigned)ls[2] | ((unsigned)ls[3] << 16);
            lo.u4.z = (unsigned)ls[4] | ((unsigned)ls[5] << 16);
            lo.u4.w = (unsigned)ls[6] | ((unsigned)ls[7] << 16);
            #pragma unroll
            for (int ot = 0; ot < 4; ++ot) {
                c[ot] = __builtin_amdgcn_mfma_f32_16x16x32_bf16(hi.v, npf[kb][ot], c[ot], 0, 0, 0);
                c[ot] = __builtin_amdgcn_mfma_f32_16x16x32_bf16(lo.v, npf[kb][ot], c[ot], 0, 0, 0);
            }
        }
        #pragma unroll
        for (int kb = 0; kb < 2; ++kb) {
            BF8 za;
            za.u4 = *(const uint4*)&xz[lm*72 + kb*32 + q*8];
            #pragma unroll
            for (int ot = 0; ot < 4; ++ot)
                c[ot] = __builtin_amdgcn_mfma_f32_16x16x32_bf16(za.v, npf[2+kb][ot], c[ot], 0, 0, 0);
        }
        // LN stats: per node r, partial over 4 ot, butterfly over lm
        float s[4], sq[4];
        #pragma unroll
        for (int r = 0; r < 4; ++r) {
            s[r]  = c[0][r] + c[1][r] + c[2][r] + c[3][r];
            sq[r] = c[0][r]*c[0][r] + c[1][r]*c[1][r] + c[2][r]*c[2][r] + c[3][r]*c[3][r];
        }
        #pragma unroll
        for (int off = 1; off < 16; off <<= 1) {
            #pragma unroll
            for (int r = 0; r < 4; ++r) {
                s[r]  += __shfl_xor(s[r], off);
                sq[r] += __shfl_xor(sq[r], off);
            }
        }
        if (lm == 0) {
            #pragma unroll
            for (int r = 0; r < 4; ++r) {
                red[grp][half][q*4 + r][0] = s[r];
                red[grp][half][q*4 + r][1] = sq[r];
            }
        }
        __syncthreads();
        #pragma unroll
        for (int r = 0; r < 4; ++r) {
            int j = q*4 + r;
            float ts = red[grp][0][j][0] + red[grp][1][j][0];
            float tq = red[grp][0][j][1] + red[grp][1][j][1];
            float mu = ts * (1.0f/128.0f);
            float var = tq * (1.0f/128.0f) - mu*mu;
            float rs = rsqrtf(var + 1e-5f);
            #pragma unroll
            for (int ot = 0; ot < 4; ++ot) {
                float y = (c[ot][r] - mu) * rs * lg[ot] + lb[ot];
                out[(size_t)(n0g + j)*128 + ob + ot*16 + lm] = silu_f(y);
            }
        }
        __syncthreads();
    }
}

// ---------------- fallback kernels (round-1 path) ----------------

__global__ __launch_bounds__(256) void edge_kernel(
    const float* __restrict__ pos, const int* __restrict__ edge_index,
    const float* __restrict__ rbf_c, const float* __restrict__ rbf_w,
    const float* __restrict__ sh_w, const float* __restrict__ sh_b,
    const float* __restrict__ w1, const float* __restrict__ b1,
    const float* __restrict__ w2, const float* __restrict__ b2,
    float* __restrict__ agg)
{
    __shared__ float sW1[2048];
    __shared__ float sW2[4096];
    __shared__ float sShW[144], sShB[16], sC[16], sWd[16], sB1[64], sB2[64];
    int tid = threadIdx.x;
    for (int i = tid; i < 2048; i += 256) sW1[i] = w1[i];
    for (int i = tid; i < 4096; i += 256) sW2[i] = w2[i];
    if (tid < 144) sShW[tid] = sh_w[tid];
    if (tid < 16) { sShB[tid] = sh_b[tid]; sC[tid] = rbf_c[tid]; sWd[tid] = rbf_w[tid]; }
    if (tid < 64) sB1[tid] = b1[tid];
    if (tid >= 64 && tid < 128) sB2[tid-64] = b2[tid-64];
    __syncthreads();

    int e = blockIdx.x * 256 + tid;
    int s   = edge_index[e];
    int dst = edge_index[NE + e];
    const float* ps = pos + 3*(size_t)s;
    const float* pd = pos + 3*(size_t)dst;
    float rx = pd[0]-ps[0], ry = pd[1]-ps[1], rz = pd[2]-ps[2];
    float feat[32];
    compute_feat(rx, ry, rz, sC, sWd, sShW, sShB, feat);

    float h2[64];
    #pragma unroll
    for (int o = 0; o < 64; ++o) h2[o] = sB2[o];

    #pragma unroll 1
    for (int jc = 0; jc < 8; ++jc) {
        float h1c[8];
        #pragma unroll
        for (int jj = 0; jj < 8; ++jj) h1c[jj] = sB1[jc*8+jj];
        #pragma unroll
        for (int k = 0; k < 32; ++k) {
            float f = feat[k];
            #pragma unroll
            for (int jj = 0; jj < 8; ++jj) h1c[jj] += f * sW1[k*64 + jc*8 + jj];
        }
        #pragma unroll
        for (int jj = 0; jj < 8; ++jj) h1c[jj] = silu_f(h1c[jj]);
        #pragma unroll
        for (int jj = 0; jj < 8; ++jj) {
            float v = h1c[jj];
            #pragma unroll
            for (int o = 0; o < 64; ++o) h2[o] += v * sW2[(jc*8+jj)*64 + o];
        }
    }
    size_t base = (size_t)s * 64;
    #pragma unroll
    for (int o = 0; o < 64; ++o)
        unsafeAtomicAdd(&agg[base + o], h2[o]);
}

__global__ __launch_bounds__(256) void zn_kernel(
    const float* __restrict__ pos, const float* __restrict__ zinc_pos,
    const float* __restrict__ rbf_c, const float* __restrict__ rbf_w,
    const float* __restrict__ sh_w, const float* __restrict__ sh_b,
    const float* __restrict__ zn_w, const float* __restrict__ zn_b,
    float* __restrict__ zn_f)
{
    __shared__ float sW[2048];
    __shared__ float sShW[144], sShB[16], sC[16], sWd[16], sB[64];
    int tid = threadIdx.x;
    for (int i = tid; i < 2048; i += 256) sW[i] = zn_w[i];
    if (tid < 144) sShW[tid] = sh_w[tid];
    if (tid < 16) { sShB[tid] = sh_b[tid]; sC[tid] = rbf_c[tid]; sWd[tid] = rbf_w[tid]; }
    if (tid < 64) sB[tid] = zn_b[tid];
    __syncthreads();
    int n = blockIdx.x * 256 + tid;
    if (n >= NN) return;
    float rx = pos[n*3+0] - zinc_pos[0];
    float ry = pos[n*3+1] - zinc_pos[1];
    float rz = pos[n*3+2] - zinc_pos[2];
    float feat[32];
    compute_feat(rx, ry, rz, sC, sWd, sShW, sShB, feat);
    #pragma unroll 1
    for (int jc = 0; jc < 8; ++jc) {
        float h[8];
        #pragma unroll
        for (int jj = 0; jj < 8; ++jj) h[jj] = sB[jc*8+jj];
        #pragma unroll
        for (int k = 0; k < 32; ++k) {
            float f = feat[k];
            #pragma unroll
            for (int jj = 0; jj < 8; ++jj) h[jj] += f * sW[k*64 + jc*8 + jj];
        }
        #pragma unroll
        for (int jj = 0; jj < 8; ++jj)
            zn_f[(size_t)n*64 + jc*8 + jj] = silu_f(h[jj]);
    }
}

__global__ __launch_bounds__(256) void out_kernel(
    const float* __restrict__ agg, const float* __restrict__ zn_f,
    const float* __restrict__ np_w, const float* __restrict__ np_b,
    const float* __restrict__ ln_g, const float* __restrict__ ln_b,
    float* __restrict__ out)
{
    __shared__ float sX[128*36];
    __shared__ float sH[32*130];
    __shared__ float sMu[32], sVar[32];
    int tid = threadIdx.x;
    int o = tid & 127;
    int nb = (tid >> 7) * 16;
    float bias = np_b[o];
    float g = ln_g[o], bta = ln_b[o];

    for (int n0 = blockIdx.x * 32; n0 < NN; n0 += gridDim.x * 32) {
        for (int i = tid; i < 4096; i += 256) {
            int n = i >> 7, k = i & 127;
            float v = (k < 64) ? agg[(size_t)(n0+n)*64 + k]
                               : zn_f[(size_t)(n0+n)*64 + (k-64)];
            sX[k*36 + n] = v;
        }
        __syncthreads();
        float acc[16];
        #pragma unroll
        for (int i = 0; i < 16; ++i) acc[i] = bias;
        #pragma unroll 4
        for (int k = 0; k < 128; ++k) {
            float w = np_w[k*128 + o];
            const float* xr = &sX[k*36 + nb];
            #pragma unroll
            for (int i = 0; i < 16; ++i) acc[i] += w * xr[i];
        }
        #pragma unroll
        for (int i = 0; i < 16; ++i) sH[(nb+i)*130 + o] = acc[i];
        __syncthreads();
        if (tid < 32) {
            float s = 0.0f, sq2 = 0.0f;
            for (int oo = 0; oo < 128; ++oo) {
                float v = sH[tid*130 + oo];
                s += v; sq2 += v*v;
            }
            float mu = s * (1.0f/128.0f);
            sMu[tid] = mu;
            sVar[tid] = sq2 * (1.0f/128.0f) - mu*mu;
        }
        __syncthreads();
        #pragma unroll
        for (int i = 0; i < 16; ++i) {
            int n = nb + i;
            float y = (acc[i] - sMu[n]) * rsqrtf(sVar[n] + 1e-5f) * g + bta;
            out[(size_t)(n0+n)*128 + o] = silu_f(y);
        }
        __syncthreads();
    }
}

extern "C" void kernel_launch(void* const* d_in, const int* in_sizes, int n_in,
                              void* d_out, int out_size, void* d_ws, size_t ws_size,
                              hipStream_t stream) {
    const float* pos   = (const float*)d_in[0];
    const float* zinc  = (const float*)d_in[1];
    const int*   ei    = (const int*)  d_in[2];
    const float* rbf_c = (const float*)d_in[3];
    const float* rbf_w = (const float*)d_in[4];
    const float* sh_w  = (const float*)d_in[5];
    const float* sh_b  = (const float*)d_in[6];
    const float* pm_w1 = (const float*)d_in[7];
    const float* pm_b1 = (const float*)d_in[8];
    const float* pm_w2 = (const float*)d_in[9];
    const float* pm_b2 = (const float*)d_in[10];
    const float* zn_w  = (const float*)d_in[11];
    const float* zn_b  = (const float*)d_in[12];
    const float* np_w  = (const float*)d_in[13];
    const float* np_b  = (const float*)d_in[14];
    const float* ln_g  = (const float*)d_in[15];
    const float* ln_b  = (const float*)d_in[16];
    float* out  = (float*)d_out;

    float* agg   = (float*)d_ws;                       // NN*64 f
    int* count   = (int*)(agg + (size_t)NN * 64);      // NN
    int* start   = count + NN;                         // NN+1
    int* rank    = start + NN + 1;                     // NE
    int* sdj     = rank + NE;                          // NE
    int* bsum    = sdj + NE;                           // 512
    float* w1e   = (float*)(bsum + 512);               // 2048
    float* b1e   = w1e + 2048;                         // 64
    float* zwe   = b1e + 64;                           // 2048
    float* zbe   = zwe + 2048;                         // 64
    size_t needed = (size_t)((char*)(zbe + 64) - (char*)d_ws);

    if (ws_size >= needed) {
        prep_kernel<<<SCAN_NB, 256, 0, stream>>>(sh_w, sh_b, pm_w1, pm_b1, zn_w, zn_b,
                                                 w1e, b1e, zwe, zbe, count);
        hist_rank_kernel<<<NE/256, 256, 0, stream>>>(ei, count, rank);
        scan1_kernel<<<SCAN_NB, 256, 0, stream>>>(count, bsum);
        scan23_kernel<<<SCAN_NB, 256, 0, stream>>>(count, bsum, start);
        scatter2_kernel<<<NE/256, 256, 0, stream>>>(ei, rank, start, sdj);
        gather_mfma5_kernel<<<GATHER_BLOCKS, 256, 0, stream>>>(
            pos, sdj, start, rbf_c, rbf_w, w1e, b1e, pm_w2, pm_b2, agg);
        out2_kernel<<<512, 256, 0, stream>>>(
            agg, pos, zinc, rbf_c, rbf_w, zwe, zbe, np_w, np_b, ln_g, ln_b, out);
    } else {
        float* zn_f = (float*)count;
        zn_kernel<<<(NN + 255)/256, 256, 0, stream>>>(
            pos, zinc, rbf_c, rbf_w, sh_w, sh_b, zn_w, zn_b, zn_f);
        hipMemsetAsync(agg, 0, (size_t)NN * 64 * sizeof(float), stream);
        edge_kernel<<<NE/256, 256, 0, stream>>>(
            pos, ei, rbf_c, rbf_w, sh_w, sh_b, pm_w1, pm_b1, pm_w2, pm_b2, agg);
        out_kernel<<<512, 256, 0, stream>>>(
            agg, zn_f, np_w, np_b, ln_g, ln_b, out);
    }
}